// Round 23
// baseline (245.701 us; speedup 1.0000x reference)
//
#include <hip/hip_runtime.h>
#include <hip/hip_bf16.h>
#include <stdint.h>

typedef __hip_bfloat16 bf16;
typedef __attribute__((ext_vector_type(8))) __bf16 bf8v;
typedef __attribute__((ext_vector_type(8))) short short8;
typedef __attribute__((ext_vector_type(4))) short short4v;
typedef __attribute__((ext_vector_type(4))) float f32x4;
#define DEVINL __device__ __forceinline__
#define MFMA16(a,b,c) __builtin_amdgcn_mfma_f32_16x16x32_bf16((a),(b),(c),0,0,0)

DEVINL short f2bs(float f) { bf16 h = __float2bfloat16(f); return *reinterpret_cast<short*>(&h); }
DEVINL float bs2f(short s) { bf16 h = *reinterpret_cast<bf16*>(&s); return __bfloat162float(h); }

// ---------------- problem dims ----------------
// B=2, C=64, H=W=128, n=16384, HEADS=8, DH=32. All device I/O buffers are f32.

// ---------------- workspace layout (BYTE offsets) ----------------
static const size_t OFF_ZBF   = 0;          // [2][384][16384] bf16 (QKV conv out, NCHW)
static const size_t OFF_WTQ   = 29360128;   // [9][384][64] bf16
static const size_t OFF_WTR1  = 29802496;   // [9][64][256] bf16
static const size_t OFF_WTR2  = 30097408;   // [9][64][64] bf16
static const size_t OFF_WTC1  = 30171136;   // [9][64][64] bf16
static const size_t OFF_WTF   = 30244864;   // [9][64][64] bf16 (folded c31 w3@w2)
static const size_t OFF_W1T   = 30318592;   // [576][64] f32 (qco_w1 transposed)
static const size_t OFF_SCAWT = 30466048;   // [64][64] f32
static const size_t OFF_T1WT  = 30482432;   // [128][64] f32
static const size_t OFF_T2WT  = 30515200;   // [64][64] f32
static const size_t OFF_GB    = 31645696;   // [2][384][384] bf16 (Gram, symmetric)
static const size_t OFF_WQLB  = 32235520;   // [256][64] bf16
static const size_t OFF_WKMB  = 32268288;   // [512][128] bf16
static const size_t OFF_WQHB  = 32399360;   // [768][192] bf16
static const size_t OFF_T1    = 41082880;   // [2][256][128] f32
static const size_t OFF_UL    = 41345024;   // [2][256][64] f32
static const size_t OFF_UK    = 41476096;   // [2][512][128] f32
static const size_t OFF_T1H   = 42000384;   // [2][768][128] f32
static const size_t OFF_UH    = 42786816;   // [2][768][192] f32
static const size_t OFF_WEL   = 44503040;   // [2][256][128] f32
static const size_t OFF_WEH   = 44765184;   // [2][768][128] f32
static const size_t OFF_ACATB = 45813760;   // [2][256][128] bf16
static const size_t OFF_TSUM  = 45944832;   // [2][64][9] f32
static const size_t OFF_ATTB  = 45949440;   // [2][64] f32
static const size_t OFF_MIDB  = 62727168;   // [2][16384][64] bf16 (px-major)
static const size_t OFF_HOUTB = 66921472;   // [2][16384][64] bf16 (px-major)
static const size_t OFF_WFFB  = 71115776;   // [4][64][64] bf16 (FF weights)
static const size_t OFF_GPART = 79504384;   // [16][2][384][384] f32 ; ALSO (later) hcatT
static const size_t OFF_HCATT = 79504384;   // [2][16384][256] bf16 (aliases GPART, dead by then)
static const size_t OFF_XT    = 98378752;   // [2][16384][64] bf16 (x transposed)
static const size_t WS_BYTES  = 102573056;

// ================= prep (weight transforms + x transpose, one launch) =================
__global__ __launch_bounds__(256) void k_prep_all(
    const float* __restrict__ wd, const float* __restrict__ wm,
    const float* __restrict__ wu, const float* __restrict__ rw1,
    const float* __restrict__ rw2, const float* __restrict__ cw1,
    const float* __restrict__ wql, const float* __restrict__ wkm,
    const float* __restrict__ wqh,
    const float* __restrict__ c31w3, const float* __restrict__ c31w2,
    const float* __restrict__ qw1, const float* __restrict__ qscaw,
    const float* __restrict__ qt1w, const float* __restrict__ qt2w,
    const float* __restrict__ f11, const float* __restrict__ f12,
    const float* __restrict__ f21, const float* __restrict__ f22,
    const float* __restrict__ x,
    bf16* __restrict__ wtq, bf16* __restrict__ wtr1,
    bf16* __restrict__ wtr2, bf16* __restrict__ wtc1,
    bf16* __restrict__ wqlb, bf16* __restrict__ wkmb,
    bf16* __restrict__ wqhb, bf16* __restrict__ wtf,
    float* __restrict__ w1t, float* __restrict__ scawt,
    float* __restrict__ t1wt, float* __restrict__ t2wt,
    bf16* __restrict__ wffb, short* __restrict__ xt) {
  __shared__ short sT[64][72];
  const int t = threadIdx.x;
  if (blockIdx.x >= 3040) {
    // ---- x [b][64][16384] f32 -> xt [b][16384][64] bf16 ----
    const int j = blockIdx.x - 3040;           // 0..511
    const int b = j >> 8, p0 = (j & 255) * 64;
    for (int i = t; i < 1024; i += 256) {
      int c = i >> 4, p4 = (i & 15) * 4;
      float4 g = *(const float4*)&x[(((size_t)(b * 64 + c)) << 14) + p0 + p4];
      sT[p4 + 0][c] = f2bs(g.x);
      sT[p4 + 1][c] = f2bs(g.y);
      sT[p4 + 2][c] = f2bs(g.z);
      sT[p4 + 3][c] = f2bs(g.w);
    }
    __syncthreads();
    for (int i = t; i < 512; i += 256) {
      int p = i >> 3, co = (i & 7) * 8;
      *(short8*)&xt[((((size_t)b << 14) + p0 + p)) * 64 + co] = *(short8*)&sT[p][co];
    }
    return;
  }
  int i = blockIdx.x * 256 + t;
  if (i < 221184) {
    int tap = i / 24576, r = i % 24576, oc = r >> 6, ic = r & 63;
    float v;
    if (oc < 64)       v = wd[(oc * 64 + ic) * 9 + tap];
    else if (oc < 192) v = wm[((oc - 64) * 64 + ic) * 9 + tap];
    else               v = wu[((oc - 192) * 64 + ic) * 9 + tap];
    wtq[i] = __float2bfloat16(v);
  } else if (i < 368640) {
    int j = i - 221184;
    int tap = j / 16384, r = j % 16384, oc = r >> 8, ic = r & 255;
    wtr1[j] = __float2bfloat16(rw1[(oc * 256 + ic) * 9 + tap]);
  } else if (i < 405504) {
    int j = i - 368640;
    int tap = j / 4096, r = j % 4096, oc = r >> 6, ic = r & 63;
    wtr2[j] = __float2bfloat16(rw2[(oc * 64 + ic) * 9 + tap]);
  } else if (i < 442368) {
    int j = i - 405504;
    int tap = j / 4096, r = j % 4096, oc = r >> 6, ic = r & 63;
    wtc1[j] = __float2bfloat16(cw1[(oc * 64 + ic) * 9 + tap]);
  } else if (i < 458752) {
    int j = i - 442368; wqlb[j] = __float2bfloat16(wql[j]);
  } else if (i < 524288) {
    int j = i - 458752; wkmb[j] = __float2bfloat16(wkm[j]);
  } else if (i < 671744) {
    int j = i - 524288; wqhb[j] = __float2bfloat16(wqh[j]);
  } else if (i < 708608) {
    int j = i - 671744;
    int tap = j / 4096, r = j % 4096, o = r >> 6, ic = r & 63;
    float s = 0.f;
    for (int m = 0; m < 64; m++)
      s = fmaf(c31w3[o * 64 + m], c31w2[(m * 64 + ic) * 9 + tap], s);
    wtf[j] = __float2bfloat16(s);
  } else if (i < 745472) {
    int o = i - 708608;
    int c = o & 63, rest = o >> 6, jj = rest / 9, tap = rest % 9;
    w1t[o] = qw1[(c * 64 + jj) * 9 + tap];
  } else if (i < 749568) {
    int o = i - 745472;
    int c = o & 63, jj = o >> 6;
    scawt[o] = qscaw[c * 64 + jj];
  } else if (i < 757760) {
    int o = i - 749568;
    int c = o & 63, jj = o >> 6;
    t1wt[o] = qt1w[c * 128 + jj];
  } else if (i < 761856) {
    int o = i - 757760;
    int c = o & 63, jj = o >> 6;
    t2wt[o] = qt2w[c * 64 + jj];
  } else if (i < 778240) {
    int j = i - 761856;
    int stage = j >> 12, r = j & 4095;
    const float* src = (stage == 0) ? f11 : (stage == 1) ? f12 : (stage == 2) ? f21 : f22;
    wffb[j] = __float2bfloat16(src[r]);
  }
}

// ========= QKV conv 64->384 (zero pad), direct-A MFMA, 192 oc/block, coalesced out ====
__global__ __launch_bounds__(256) void k_convq(
    const short* __restrict__ xt, const short* __restrict__ wtq,
    bf16* __restrict__ zbf)
{
  __shared__ short sX[3][130][72];   // 28080 shorts; reused as 192x132 output staging
  const int t = threadIdx.x, lane = t & 63, wv = t >> 6;
  const int y = blockIdx.x, ocg = blockIdx.y, b = blockIdx.z;

  for (int i = t; i < 3120; i += 256) {
    int ko = i & 7, c2 = i >> 3, col = c2 % 130, row = c2 / 130;
    int gy = y + row - 1, gx = col - 1;
    short8 vv;
    if ((gy >= 0) & (gy < 128) & (gx >= 0) & (gx < 128)) {
      vv = *(const short8*)&xt[((size_t)b * 1048576 + (size_t)((gy << 7) + gx) * 64) + ko * 8];
    } else {
#pragma unroll
      for (int u = 0; u < 8; u++) vv[u] = 0;
    }
    *(short8*)&sX[row][col][ko * 8] = vv;
  }
  __syncthreads();

  const f32x4 zero = {0.f, 0.f, 0.f, 0.f};
  f32x4 acc[3][8];
#pragma unroll
  for (int m = 0; m < 3; m++)
#pragma unroll
    for (int n = 0; n < 8; n++) acc[m][n] = zero;

#pragma unroll
  for (int tap = 0; tap < 9; tap++) {
    const int ky = tap / 3, kx = tap % 3;
#pragma unroll
    for (int kk = 0; kk < 2; kk++) {
      const int kb = kk * 32 + (lane >> 4) * 8;
      bf8v a0 = *(const bf8v*)&wtq[(size_t)((tap * 384 + ocg * 192 + wv * 48 + (lane & 15)) * 64) + kb];
      bf8v a1 = *(const bf8v*)&wtq[(size_t)((tap * 384 + ocg * 192 + wv * 48 + 16 + (lane & 15)) * 64) + kb];
      bf8v a2 = *(const bf8v*)&wtq[(size_t)((tap * 384 + ocg * 192 + wv * 48 + 32 + (lane & 15)) * 64) + kb];
#pragma unroll
      for (int n = 0; n < 8; n++) {
        bf8v bfr = *(const bf8v*)&sX[ky][n * 16 + (lane & 15) + kx][kb];
        acc[0][n] = MFMA16(a0, bfr, acc[0][n]);
        acc[1][n] = MFMA16(a1, bfr, acc[1][n]);
        acc[2][n] = MFMA16(a2, bfr, acc[2][n]);
      }
    }
  }
  // epilogue: stage [192 oc][128 px] bf16 tile in LDS, write coalesced 256B rows
  __syncthreads();
  short* sO = &sX[0][0][0];   // needs 192*132 = 25344 shorts <= 28080
#pragma unroll
  for (int m = 0; m < 3; m++) {
    const int ocl = wv * 48 + m * 16 + ((lane >> 4) << 2);
#pragma unroll
    for (int n = 0; n < 8; n++) {
      const int px = n * 16 + (lane & 15);
      sO[(ocl + 0) * 132 + px] = f2bs(acc[m][n][0]);
      sO[(ocl + 1) * 132 + px] = f2bs(acc[m][n][1]);
      sO[(ocl + 2) * 132 + px] = f2bs(acc[m][n][2]);
      sO[(ocl + 3) * 132 + px] = f2bs(acc[m][n][3]);
    }
  }
  __syncthreads();
  for (int i = t; i < 3072; i += 256) {
    int ocl = i >> 4, px8 = (i & 15) * 8;
    *(short8*)&zbf[(((size_t)(b * 384 + ocg * 192 + ocl)) << 14) + (y << 7) + px8] =
        *(short8*)&sO[ocl * 132 + px8];
  }
}

// ================= 3x3 reflect conv -> 64 out (direct-A MFMA, px-major IO) =================
template<int EPI>
__global__ __launch_bounds__(256) void k_conv64(
    const short* __restrict__ in, int str, long bstride, int Cin,
    const short* __restrict__ Wt,
    short* __restrict__ outb,
    const float* __restrict__ prelu_a)
{
  __shared__ short sX[3][66][72];
  const int t = threadIdx.x, lane = t & 63, wv = t >> 6;
  const int y = blockIdx.x, x0 = blockIdx.y * 64, b = blockIdx.z;

  const f32x4 zero = {0.f, 0.f, 0.f, 0.f};
  f32x4 acc[4] = {zero, zero, zero, zero};

  for (int icb = 0; icb < Cin; icb += 64) {
    __syncthreads();
    for (int i = t; i < 1584; i += 256) {
      int ko = i & 7, c2 = i >> 3, col = c2 % 66, row = c2 / 66;
      int gy = y + row - 1, gx = x0 + col - 1;
      gy = gy < 0 ? 1 : (gy > 127 ? 126 : gy);
      gx = gx < 0 ? 1 : (gx > 127 ? 126 : gx);
      *(short8*)&sX[row][col][ko * 8] =
          *(const short8*)&in[(size_t)b * bstride + (size_t)((gy << 7) + gx) * str + icb + ko * 8];
    }
    __syncthreads();
#pragma unroll
    for (int tap = 0; tap < 9; tap++) {
      const int ky = tap / 3, kx = tap % 3;
#pragma unroll
      for (int kk = 0; kk < 2; kk++) {
        const int kb = kk * 32 + (lane >> 4) * 8;
        bf8v afr = *(const bf8v*)&Wt[(size_t)(tap * 64 + wv * 16 + (lane & 15)) * Cin + icb + kb];
#pragma unroll
        for (int n = 0; n < 4; n++) {
          bf8v bfr = *(const bf8v*)&sX[ky][n * 16 + (lane & 15) + kx][kb];
          acc[n] = MFMA16(afr, bfr, acc[n]);
        }
      }
    }
  }
  const int oc0 = wv * 16 + ((lane >> 4) << 2);
  const float aP = (EPI == 1) ? prelu_a[0] : 0.f;
#pragma unroll
  for (int n = 0; n < 4; n++) {
    const int gpx = (y << 7) + x0 + n * 16 + (lane & 15);
    short4v ss;
#pragma unroll
    for (int r = 0; r < 4; r++) {
      float v = acc[n][r];
      if (EPI == 1) v = v > 0.f ? v : aP * v;
      ss[r] = f2bs(v);
    }
    *(short4v*)&outb[((size_t)(b * 16384 + gpx)) * 64 + oc0] = ss;
  }
}

// ======= fused final conv (folded c31_w2@w3) + combine + double-FF -> d_out =======
__global__ __launch_bounds__(256) void k_convff(
    const short* __restrict__ in,
    const short* __restrict__ Wt,
    const short* __restrict__ houtpm,
    const float* __restrict__ attb,
    const float* __restrict__ x_nchw,
    const short* __restrict__ wffb,
    const float* __restrict__ g1, const float* __restrict__ be1,
    const float* __restrict__ b11, const float* __restrict__ b12,
    const float* __restrict__ g2, const float* __restrict__ be2,
    const float* __restrict__ b21, const float* __restrict__ b22,
    float* __restrict__ outp)
{
  __shared__ short sX[3][66][72];
  __shared__ float sv[64][68];
  __shared__ short sy[64][72];
  __shared__ float spar[8][64];
  const int t = threadIdx.x, lane = t & 63, wv = t >> 6;
  const int y = blockIdx.x, x0 = blockIdx.y * 64, b = blockIdx.z;

  if (t < 64) {
    spar[0][t] = g1[t]; spar[1][t] = be1[t]; spar[2][t] = b11[t]; spar[3][t] = b12[t];
    spar[4][t] = g2[t]; spar[5][t] = be2[t]; spar[6][t] = b21[t]; spar[7][t] = b22[t];
  }
  for (int i = t; i < 1584; i += 256) {
    int ko = i & 7, c2 = i >> 3, col = c2 % 66, row = c2 / 66;
    int gy = y + row - 1, gx = x0 + col - 1;
    gy = gy < 0 ? 1 : (gy > 127 ? 126 : gy);
    gx = gx < 0 ? 1 : (gx > 127 ? 126 : gx);
    *(short8*)&sX[row][col][ko * 8] =
        *(const short8*)&in[(size_t)b * 1048576 + (size_t)((gy << 7) + gx) * 64 + ko * 8];
  }
  __syncthreads();

  const f32x4 zero = {0.f, 0.f, 0.f, 0.f};
  {
    f32x4 cacc[4] = {zero, zero, zero, zero};
#pragma unroll
    for (int tap = 0; tap < 9; tap++) {
      const int ky = tap / 3, kx = tap % 3;
#pragma unroll
      for (int kk = 0; kk < 2; kk++) {
        const int kb = kk * 32 + (lane >> 4) * 8;
        bf8v afr = *(const bf8v*)&Wt[(size_t)(tap * 64 + wv * 16 + (lane & 15)) * 64 + kb];
#pragma unroll
        for (int n = 0; n < 4; n++) {
          bf8v bfr = *(const bf8v*)&sX[ky][n * 16 + (lane & 15) + kx][kb];
          cacc[n] = MFMA16(afr, bfr, cacc[n]);
        }
      }
    }
    const int oc0 = wv * 16 + ((lane >> 4) << 2);
    float4 av = *(const float4*)&attb[b * 64 + oc0];
#pragma unroll
    for (int n = 0; n < 4; n++) {
      const int pxl = n * 16 + (lane & 15);
      const int gpx = (y << 7) + x0 + pxl;
      short4v hv = *(const short4v*)&houtpm[((size_t)(b * 16384 + gpx)) * 64 + oc0];
#pragma unroll
      for (int r = 0; r < 4; r++)
        sv[pxl][oc0 + r] = cacc[n][r] + bs2f(hv[r]) * (&av.x)[r] +
                           x_nchw[(((size_t)(b * 64 + oc0 + r)) << 14) + gpx];
    }
  }
  __syncthreads();

  const int chq = ((lane >> 4) << 2);
  const int pxl = wv * 16 + (lane & 15);
  float4 vv[4];
#pragma unroll
  for (int m = 0; m < 4; m++) vv[m] = *(const float4*)&sv[pxl][m * 16 + chq];

  f32x4 facc[4];

#define LN_F(SRCV, GI, BI)                                                      \
  {                                                                             \
    float s1 = 0.f, s2 = 0.f;                                                   \
    _Pragma("unroll")                                                           \
    for (int m = 0; m < 4; m++)                                                 \
      _Pragma("unroll")                                                         \
      for (int r = 0; r < 4; r++) {                                             \
        float vx = (&SRCV[m].x)[r];                                             \
        s1 += vx; s2 += vx * vx;                                                \
      }                                                                         \
    s1 += __shfl_xor(s1, 16); s1 += __shfl_xor(s1, 32);                         \
    s2 += __shfl_xor(s2, 16); s2 += __shfl_xor(s2, 32);                         \
    float mu = s1 * (1.f / 64.f);                                               \
    float var = fmaxf(s2 * (1.f / 64.f) - mu * mu, 0.f);                        \
    float rstd = 1.f / sqrtf(var + 1e-5f);                                      \
    _Pragma("unroll")                                                           \
    for (int m = 0; m < 4; m++) {                                               \
      short4v ss;                                                               \
      _Pragma("unroll")                                                         \
      for (int r = 0; r < 4; r++) {                                             \
        int ch = m * 16 + chq + r;                                              \
        ss[r] = f2bs(((&SRCV[m].x)[r] - mu) * rstd * spar[GI][ch] + spar[BI][ch]); \
      }                                                                         \
      *(short4v*)&sy[pxl][m * 16 + chq] = ss;                                   \
    }                                                                           \
  }

#define MM_F(SIDX)                                                              \
  {                                                                             \
    _Pragma("unroll")                                                           \
    for (int m = 0; m < 4; m++) facc[m] = zero;                                 \
    _Pragma("unroll")                                                           \
    for (int kk = 0; kk < 2; kk++) {                                            \
      const int kb = kk * 32 + (lane >> 4) * 8;                                 \
      bf8v bfr = *(const bf8v*)&sy[wv * 16 + (lane & 15)][kb];                  \
      _Pragma("unroll")                                                         \
      for (int m = 0; m < 4; m++) {                                             \
        bf8v afr = *(const bf8v*)&wffb[(size_t)(SIDX) * 4096 +                  \
                                       (m * 16 + (lane & 15)) * 64 + kb];       \
        facc[m] = MFMA16(afr, bfr, facc[m]);                                    \
      }                                                                         \
    }                                                                           \
  }

  LN_F(vv, 0, 1);
  MM_F(0);
#pragma unroll
  for (int m = 0; m < 4; m++) {
    short4v ss;
#pragma unroll
    for (int r = 0; r < 4; r++) {
      float h = facc[m][r] + spar[2][m * 16 + chq + r];
      h = h > 0.f ? h : 0.01f * h;
      ss[r] = f2bs(h);
    }
    *(short4v*)&sy[pxl][m * 16 + chq] = ss;
  }
  MM_F(1);
  float4 o2v[4];
#pragma unroll
  for (int m = 0; m < 4; m++)
#pragma unroll
    for (int r = 0; r < 4; r++)
      (&o2v[m].x)[r] = facc[m][r] + spar[3][m * 16 + chq + r] + (&vv[m].x)[r];
  LN_F(o2v, 4, 5);
  MM_F(2);
#pragma unroll
  for (int m = 0; m < 4; m++) {
    short4v ss;
#pragma unroll
    for (int r = 0; r < 4; r++) {
      float h = facc[m][r] + spar[6][m * 16 + chq + r];
      h = h > 0.f ? h : 0.01f * h;
      ss[r] = f2bs(h);
    }
    *(short4v*)&sy[pxl][m * 16 + chq] = ss;
  }
  MM_F(3);
  const int gpx = (y << 7) + x0 + pxl;
#pragma unroll
  for (int m = 0; m < 4; m++)
#pragma unroll
    for (int r = 0; r < 4; r++) {
      const int ch = m * 16 + chq + r;
      outp[(((size_t)(b * 64 + ch)) << 14) + gpx] =
          facc[m][r] + spar[7][ch] + (&vv[m].x)[r];
    }
#undef LN_F
#undef MM_F
}

// ======= Gram via MFMA: G[b] = Z Z^T (18 needed pairs x 16 k-chunks of 1024) =======
// XCD-grouped swizzle: all 18 pair-blocks of one (kc,b) group land on one XCD slot
__global__ __launch_bounds__(256) void k_gramm(const short* __restrict__ Z,
                                               float* __restrict__ Gp) {
  static const char TIa[18] = {0,0,0,1,1,2,1,1,1,2,2,2,3,3,3,4,4,5};
  static const char TJa[18] = {0,1,2,1,2,2,3,4,5,3,4,5,3,4,5,4,5,5};
  const int L = blockIdx.x;
  const int xcd = L & 7;
  const int rest = L >> 3;
  const int p = rest % 18;
  const int ghi = rest / 18;
  const int g = xcd + 8 * ghi;        // 0..31
  const int kc = g & 15, b = g >> 4;
  const int ti = TIa[p], tj = TJa[p];
  const bool diag = (ti == tj);
  __shared__ short sA[64][72];
  __shared__ short sB[64][72];
  short (*sBp)[72] = diag ? sA : sB;
  const int t = threadIdx.x, lane = t & 63, wv = t >> 6;
  const int wo = wv & 1, wp = wv >> 1;
  const f32x4 zero = {0.f, 0.f, 0.f, 0.f};
  f32x4 acc[2][2];
#pragma unroll
  for (int m = 0; m < 2; m++)
#pragma unroll
    for (int n = 0; n < 2; n++) acc[m][n] = zero;
  const size_t zb = (size_t)b * 6291456;
  const int k0 = kc * 1024;
  for (int ks = 0; ks < 1024; ks += 64) {
    __syncthreads();
    for (int i = t; i < 512; i += 256) {
      int r = i >> 3, ko = i & 7;
      *(short8*)&sA[r][ko * 8] =
          *(const short8*)&Z[zb + ((size_t)(ti * 64 + r) << 14) + k0 + ks + ko * 8];
      if (!diag)
        *(short8*)&sB[r][ko * 8] =
            *(const short8*)&Z[zb + ((size_t)(tj * 64 + r) << 14) + k0 + ks + ko * 8];
    }
    __syncthreads();
#pragma unroll
    for (int kk = 0; kk < 2; kk++) {
      const int kb = kk * 32 + (lane >> 4) * 8;
      bf8v bfr[2];
#pragma unroll
      for (int n = 0; n < 2; n++)
        bfr[n] = *(const bf8v*)&sBp[wp * 32 + n * 16 + (lane & 15)][kb];
#pragma unroll
      for (int m = 0; m < 2; m++) {
        bf8v afr = *(const bf8v*)&sA[wo * 32 + m * 16 + (lane & 15)][kb];
#pragma unroll
        for (int n = 0; n < 2; n++)
          acc[m][n] = MFMA16(afr, bfr[n], acc[m][n]);
      }
    }
  }
  float* gp = Gp + ((size_t)(kc * 2 + b)) * 147456;
#pragma unroll
  for (int m = 0; m < 2; m++)
#pragma unroll
    for (int n = 0; n < 2; n++)
#pragma unroll
      for (int r = 0; r < 4; r++) {
        const int row = ti * 64 + wo * 32 + m * 16 + ((lane >> 4) << 2) + r;
        const int col = tj * 64 + wp * 32 + n * 16 + (lane & 15);
        float v = acc[m][n][r];
        gp[(size_t)row * 384 + col] = v;
        if (ti != tj) gp[(size_t)col * 384 + row] = v;
      }
}

// ======= merged: reduce partials (16) -> bf16 Gb  |  QCO tap sums =======
__global__ __launch_bounds__(256) void k_gt(const float* __restrict__ Gp,
                                            bf16* __restrict__ Gb,
                                            const bf16* __restrict__ Z,
                                            float* __restrict__ Tsum) {
  __shared__ float sc[16];
  __shared__ float red[4][9];
  const int t = threadIdx.x;
  if (blockIdx.x < 1152) {
    int i = blockIdx.x * 256 + t;
    if (i >= 294912) return;
    int b = i / 147456, e = i % 147456;
    float s = 0.f;
#pragma unroll
    for (int c = 0; c < 16; c++) s += Gp[(size_t)(c * 2 + b) * 147456 + e];
    Gb[(size_t)b * 147456 + e] = __float2bfloat16(s);
    return;
  }
  const int bid = blockIdx.x - 1152;
  const int c = bid & 63, b = bid >> 6;
  const bf16* src = Z + (((size_t)(b * 384 + c)) << 14);
  float a9[9] = {};
  for (int i = t; i < 2048; i += 256) {
    int y = i >> 4, x0 = (i & 15) * 8;
    short8 v8 = *(const short8*)&src[(y << 7) + x0];
    float vs[8], s8 = 0.f;
#pragma unroll
    for (int u = 0; u < 8; u++) { vs[u] = bs2f(v8[u]); s8 += vs[u]; }
    a9[0] += s8;
    int ri = (y == 0) ? 0 : (y == 1) ? 1 : (y == 126) ? 2 : (y == 127) ? 3 : -1;
    if (ri >= 0) a9[1 + ri] += s8;
    if (x0 == 0)   { a9[5] += vs[0]; a9[6] += vs[1]; }
    if (x0 == 120) { a9[7] += vs[6]; a9[8] += vs[7]; }
    if (ri >= 0) {
      if (x0 == 0)   { sc[ri * 4 + 0] = vs[0]; sc[ri * 4 + 1] = vs[1]; }
      if (x0 == 120) { sc[ri * 4 + 2] = vs[6]; sc[ri * 4 + 3] = vs[7]; }
    }
  }
#pragma unroll
  for (int q = 0; q < 9; q++)
#pragma unroll
    for (int o = 32; o; o >>= 1) a9[q] += __shfl_xor(a9[q], o);
  const int w = t >> 6;
  if ((t & 63) == 0)
#pragma unroll
    for (int q = 0; q < 9; q++) red[w][q] = a9[q];
  __syncthreads();
  if (t == 0) {
    float s9[9];
#pragma unroll
    for (int q = 0; q < 9; q++) s9[q] = red[0][q] + red[1][q] + red[2][q] + red[3][q];
    const float T = s9[0];
    float R[4] = {s9[1], s9[2], s9[3], s9[4]};
    const float C0 = s9[5], C1 = s9[6], C126 = s9[7], C127 = s9[8];
    float rs[4][3];
#pragma unroll
    for (int ri = 0; ri < 4; ri++) {
      rs[ri][0] = R[ri] - sc[ri * 4 + 3] + sc[ri * 4 + 1];
      rs[ri][1] = R[ri];
      rs[ri][2] = R[ri] - sc[ri * 4 + 0] + sc[ri * 4 + 2];
    }
    float A3[3] = {T - C127 + C1, T, T - C0 + C126};
#pragma unroll
    for (int dx = 0; dx < 3; dx++) {
      Tsum[bid * 9 + 0 * 3 + dx] = A3[dx] - rs[3][dx] + rs[1][dx];
      Tsum[bid * 9 + 1 * 3 + dx] = A3[dx];
      Tsum[bid * 9 + 2 * 3 + dx] = A3[dx] - rs[0][dx] + rs[2][dx];
    }
  }
}

// ======= MFMA solve chain (5 jobs): C = W[M,K] * G[r0:r0+K, c0:c0+N] =======
struct MJobs5 {
  const short* A[5];
  float* C[5];
  int lda[5], K[5], r0[5], c0[5], ldc[5];
  long sC[5];
  int nx[5], b0[6];
};

__global__ __launch_bounds__(256) void k_mgemm5(MJobs5 J, const short* __restrict__ Gb) {
  const int bx = blockIdx.x, z = blockIdx.y;
  int j = 0;
  while (bx >= J.b0[j + 1]) j++;
  const int local = bx - J.b0[j];
  const int xn = local % J.nx[j], ym = local / J.nx[j];
  const int t = threadIdx.x, lane = t & 63, wv = t >> 6;
  const short* Gp = Gb + (size_t)z * 147456;
  const short* Ap = J.A[j];
  const int K = J.K[j], lda = J.lda[j];
  const int m0 = ym * 64 + wv * 16, n0 = xn * 64;
  const int gc0 = J.c0[j] + n0, r0 = J.r0[j];
  const f32x4 zero = {0.f, 0.f, 0.f, 0.f};
  f32x4 acc[4] = {zero, zero, zero, zero};
  for (int kk = 0; kk < K; kk += 32) {
    const int kb = kk + (lane >> 4) * 8;
    bf8v afr = *(const bf8v*)&Ap[(size_t)(m0 + (lane & 15)) * lda + kb];
#pragma unroll
    for (int n = 0; n < 4; n++) {
      bf8v bfr = *(const bf8v*)&Gp[(size_t)(gc0 + n * 16 + (lane & 15)) * 384 + r0 + kb];
      acc[n] = MFMA16(afr, bfr, acc[n]);
    }
  }
  float* Cp = J.C[j] + (size_t)z * J.sC[j];
  const int mq = m0 + ((lane >> 4) << 2);
#pragma unroll
  for (int n = 0; n < 4; n++) {
    const int nc = n0 + n * 16 + (lane & 15);
#pragma unroll
    for (int r = 0; r < 4; r++)
      Cp[(size_t)(mq + r) * J.ldc[j] + nc] = acc[n][r];
  }
}

// ===== per-pixel map via MFMA, DIRECT px-major output (transph folded in) =====
// view-quirk: linear idx Lg = (oc<64 ? px*64+oc : 1048576+px*192+(oc-64));
// NCHW view c = Lg>>14, p = Lg&16383; write hcatT[b][p][c].
__global__ __launch_bounds__(256) void k_pixm(
    const short* __restrict__ Z, const short* __restrict__ Acatb,
    const float* __restrict__ bl, const float* __restrict__ bh,
    short* __restrict__ hcatT)
{
  const int p0 = blockIdx.x * 64, ocg = blockIdx.y, b = blockIdx.z;
  __shared__ short sA[64][136];
  __shared__ short sB[64][136];
  const int t = threadIdx.x, lane = t & 63, wv = t >> 6;
  for (int i = t; i < 1024; i += 256) {
    int oc = i >> 4, ko = i & 15;
    *(short8*)&sA[oc][ko * 8] =
        *(const short8*)&Acatb[((size_t)(b * 256 + ocg * 64 + oc)) * 128 + ko * 8];
  }
  for (int i = t; i < 1024; i += 256) {
    int px = i & 63, ko = i >> 6;
    short8 vv;
#pragma unroll
    for (int u = 0; u < 8; u++)
      vv[u] = Z[((size_t)(b * 384 + 64 + ko * 8 + u) << 14) + p0 + px];
    *(short8*)&sB[px][ko * 8] = vv;
  }
  __syncthreads();
  const f32x4 zero = {0.f, 0.f, 0.f, 0.f};
  f32x4 acc[4] = {zero, zero, zero, zero};
#pragma unroll
  for (int kk = 0; kk < 4; kk++) {
    const int kb = kk * 32 + (lane >> 4) * 8;
    bf8v afr = *(const bf8v*)&sA[wv * 16 + (lane & 15)][kb];
#pragma unroll
    for (int n = 0; n < 4; n++) {
      bf8v bfr = *(const bf8v*)&sB[n * 16 + (lane & 15)][kb];
      acc[n] = MFMA16(afr, bfr, acc[n]);
    }
  }
  const size_t hb = (size_t)b * 16384;
#pragma unroll
  for (int n = 0; n < 4; n++) {
    const int px = p0 + n * 16 + (lane & 15);
#pragma unroll
    for (int r = 0; r < 4; r++) {
      const int oc = ocg * 64 + wv * 16 + ((lane >> 4) << 2) + r;
      float v = acc[n][r] + (oc < 64 ? bl[oc] : bh[oc - 64]);
      const int Lg = (oc < 64) ? (px << 6) + oc
                               : 1048576 + px * 192 + (oc - 64);
      const int c = Lg >> 14, pp = Lg & 16383;
      hcatT[(hb + pp) * 256 + c] = f2bs(v);
    }
  }
}

// ================= proj GEMMs (2 jobs) -> bf16 Acat =================
struct Jobs2 {
  const float* A[2]; const float* B[2];
  int K[2]; int lda[2];
  long sB[2];
  int nx[2]; int b0[3]; int co[2];
};

__global__ __launch_bounds__(256) void k_sgemm2b(Jobs2 J, bf16* __restrict__ Cb) {
  __shared__ float sa[16][17];
  __shared__ float sb[16][17];
  const int bx = blockIdx.x, z = blockIdx.y;
  int j = (bx >= J.b0[1]) ? 1 : 0;
  const int local = bx - J.b0[j];
  const int x = local % J.nx[j], y = local / J.nx[j];
  const int tx = threadIdx.x & 15, ty = threadIdx.x >> 4;
  const float* Ap = J.A[j];
  const float* Bp = J.B[j] + (size_t)z * J.sB[j];
  const int K = J.K[j], lda = J.lda[j];
  const int m = y * 16 + ty, n = x * 16 + tx;
  float acc = 0.f;
  for (int k0 = 0; k0 < K; k0 += 16) {
    sa[ty][tx] = Ap[(size_t)m * lda + k0 + tx];
    sb[ty][tx] = Bp[(size_t)(k0 + ty) * 128 + n];
    __syncthreads();
#pragma unroll
    for (int kk = 0; kk < 16; kk++) acc = fmaf(sa[ty][kk], sb[kk][tx], acc);
    __syncthreads();
  }
  Cb[(size_t)z * 32768 + J.co[j] + (size_t)m * 128 + n] = __float2bfloat16(acc);
}

// ======= merged attention (512 threads): float4 LDS dots, 4-row K reuse | QCO tail =======
// grid (33, 2): bx<32 -> attn block (h=bx>>2, cy=bx&3), bx==32 -> QCO tail (b=blockIdx.y)
__global__ __launch_bounds__(512) void k_attnw(
    const float* __restrict__ T1, const float* __restrict__ T1H,
    const float* __restrict__ UL, const float* __restrict__ UK,
    const float* __restrict__ UH,
    const float* __restrict__ wql, const float* __restrict__ wkm,
    const float* __restrict__ wqh, const float* __restrict__ wvm,
    const float* __restrict__ rescale,
    float* __restrict__ WeL, float* __restrict__ WeH,
    const float* __restrict__ Tsum, const float* __restrict__ w1t,
    const float* __restrict__ scawt, const float* __restrict__ scab,
    const float* __restrict__ t1wt, const float* __restrict__ t1b,
    const float* __restrict__ t2wt, const float* __restrict__ t2b,
    float* __restrict__ attb)
{
  __shared__ float sK[64 * 132];
  __shared__ float sQ[32 * 132];
  __shared__ float sAt[32 * 64];
  __shared__ float sNk[64];
  __shared__ float sNq[32];
  __shared__ float sm[64], sxq[64], scat[128], sh1[64];
  const int t = threadIdx.x, b = blockIdx.y;

  if (blockIdx.x == 32) {
    // ---- QCO tail; only t<64 computes, all threads hit barriers ----
    const int c = t;
    if (t < 64) {
      float acc = 0.f;
      for (int j = 0; j < 64; j++) {
#pragma unroll
        for (int tap = 0; tap < 9; tap++)
          acc = fmaf(w1t[((j * 9 + tap) << 6) + c], Tsum[(b * 64 + j) * 9 + tap], acc);
      }
      sm[c] = acc * (1.f / 16384.f);
    }
    __syncthreads();
    if (t < 64) {
      float xa = scab[c];
      for (int j = 0; j < 64; j++) xa = fmaf(scawt[(j << 6) + c], sm[j], xa);
      sxq[c] = xa;
    }
    __syncthreads();
    if (t < 64) {
      float xa = sxq[c];
      float mn = xa, mx = xa;
#pragma unroll
      for (int o = 32; o; o >>= 1) {
        mn = fminf(mn, __shfl_xor(mn, o));
        mx = fmaxf(mx, __shfl_xor(mx, o));
      }
      float inter = (mx - mn) * (1.f / 64.f);
      float ql = (2.f * c + 1.f) / 128.f * (mx - mn) + mn;
      float sta = 0.f;
      for (int j = 0; j < 64; j++) {
        float q = 1.f - fabsf(ql - sxq[j]);
        sta += (q > 1.f - inter) ? q : 0.f;
      }
      float tot = sta;
#pragma unroll
      for (int o = 32; o; o >>= 1) tot += __shfl_xor(tot, o);
      sta = sta / fmaxf(tot, 1e-30f);
      scat[c] = sta; scat[64 + c] = xa;
    }
    __syncthreads();
    if (t < 64) {
      float h = t1b[c];
      for (int j = 0; j < 128; j++) h = fmaf(t1wt[(j << 6) + c], scat[j], h);
      h = fmaxf(h, 0.f);
      sh1[c] = h;
    }
    __syncthreads();
    if (t < 64) {
      float o2 = t2b[c];
      for (int j = 0; j < 64; j++) o2 = fmaf(t2wt[(j << 6) + c], sh1[j], o2);
      attb[b * 64 + c] = fmaxf(o2, 0.f);
    }
    return;
  }

  const int h = blockIdx.x >> 2, cy = blockIdx.x & 3;
  const int isL = (cy == 0);
  const int rbase = isL ? 0 : (cy - 1) * 32;
  const float* TQ = isL ? (T1 + (size_t)(b * 256 + h * 32) * 128)
                        : (T1H + (size_t)(b * 768 + h * 96 + rbase) * 128);
  for (int idx = t; idx < 8192; idx += 512) {
    int e = idx >> 7, k = idx & 127;
    sK[e * 132 + k] = wkm[(size_t)(h * 64 + e) * 128 + k];
  }
  for (int idx = t; idx < 4096; idx += 512) {
    int r = idx >> 7, k = idx & 127;
    sQ[r * 132 + k] = TQ[(size_t)r * 128 + k];
  }
  __syncthreads();

  // inline norms: per-thread serial dots with float4 loads (same summation order)
  if (t < 64) {
    const float4* u4 = (const float4*)(UK + (size_t)(b * 512 + h * 64 + t) * 128);
    const float4* k4 = (const float4*)&sK[t * 132];
    float s = 0.f;
    for (int q = 0; q < 32; q++) {
      float4 a = u4[q], c = k4[q];
      s = fmaf(a.x, c.x, s); s = fmaf(a.y, c.y, s);
      s = fmaf(a.z, c.z, s); s = fmaf(a.w, c.w, s);
    }
    sNk[t] = fmaxf(sqrtf(fmaxf(s, 0.f)), 1e-12f);
  } else if (t >= 128 && t < 160) {
    const int r = t - 128;
    const float* u; const float* wv; int K;
    if (isL) { K = 64;  u = UL + (size_t)(b * 256 + h * 32 + r) * 64;
               wv = wql + (size_t)(h * 32 + r) * 64; }
    else     { K = 192; u = UH + (size_t)(b * 768 + h * 96 + rbase + r) * 192;
               wv = wqh + (size_t)(h * 96 + rbase + r) * 192; }
    const float4* u4 = (const float4*)u;
    const float4* w4 = (const float4*)wv;
    float s = 0.f;
    for (int q = 0; q < (K >> 2); q++) {
      float4 a = u4[q], c = w4[q];
      s = fmaf(a.x, c.x, s); s = fmaf(a.y, c.y, s);
      s = fmaf(a.z, c.z, s); s = fmaf(a.w, c.w, s);
    }
    sNq[r] = fmaxf(sqrtf(fmaxf(s, 0.f)), 1e-12f);
  }
  __syncthreads();

  const int w = t >> 6, lane = t & 63;   // 8 waves
  const float rs = rescale[h];
  {
    // 4 rows per wave (w, w+8, w+16, w+24), K row loaded once per q
    const float4* k4 = (const float4*)&sK[lane * 132];
    const float4* q40 = (const float4*)&sQ[(w)      * 132];
    const float4* q41 = (const float4*)&sQ[(w + 8)  * 132];
    const float4* q42 = (const float4*)&sQ[(w + 16) * 132];
    const float4* q43 = (const float4*)&sQ[(w + 24) * 132];
    float s0 = 0.f, s1 = 0.f, s2 = 0.f, s3 = 0.f;
#pragma unroll
    for (int q = 0; q < 32; q++) {
      float4 c = k4[q];
      float4 a;
      a = q40[q]; s0 = fmaf(a.x, c.x, s0); s0 = fmaf(a.y, c.y, s0);
                  s0 = fmaf(a.z, c.z, s0); s0 = fmaf(a.w, c.w, s0);
      a = q41[q]; s1 = fmaf(a.x, c.x, s1); s1 = fmaf(a.y, c.y, s1);
                  s1 = fmaf(a.z, c.z, s1); s1 = fmaf(a.w, c.w, s1);
      a = q42[q]; s2 = fmaf(a.x, c.x, s2); s2 = fmaf(a.y, c.y, s2);
                  s2 = fmaf(a.z, c.z, s2); s2 = fmaf(a.w, c.w, s2);
      a = q43[q]; s3 = fmaf(a.x, c.x, s3); s3 = fmaf(a.y, c.y, s3);
                  s3 = fmaf(a.z, c.z, s3); s3 = fmaf(a.w, c.w, s3);
    }
    float ss[4] = {s0, s1, s2, s3};
#pragma unroll
    for (int j = 0; j < 4; j++) {
      const int r = w + j * 8;
      float logit = ss[j] / (sNq[r] * sNk[lane]) * rs;
      float m = logit;
#pragma unroll
      for (int o = 32; o; o >>= 1) m = fmaxf(m, __shfl_xor(m, o));
      float p = __expf(logit - m);
      float den = p;
#pragma unroll
      for (int o = 32; o; o >>= 1) den += __shfl_xor(den, o);
      sAt[r * 64 + lane] = p / den;
    }
  }
  __syncthreads();

  // Weff rows: V read direct from global (L2-resident), float4 coalesced
  const int jg = t & 31, rw = t >> 5;
  const float* Vh = wvm + (size_t)(h * 64) * 128;
  float* dst = isL ? (WeL + (size_t)(b * 256 + h * 32) * 128)
                   : (WeH + (size_t)(b * 768 + h * 96 + rbase) * 128);
  for (int r = rw; r < 32; r += 16) {
    float4 acc = make_float4(0.f, 0.f, 0.f, 0.f);
    for (int e = 0; e < 64; e++) {
      float a = sAt[r * 64 + e];
      float4 v4 = *(const float4*)&Vh[(size_t)e * 128 + jg * 4];
      acc.x = fmaf(a, v4.x, acc.x);
      acc.y = fmaf(a, v4.y, acc.y);
      acc.z = fmaf(a, v4.z, acc.z);
      acc.w = fmaf(a, v4.w, acc.w);
    }
    *(float4*)&dst[(size_t)r * 128 + jg * 4] = acc;
  }
}

// ================= launcher =================
extern "C" void kernel_launch(void* const* d_in, const int* in_sizes, int n_in,
                              void* d_out, int out_size, void* d_ws, size_t ws_size,
                              hipStream_t stream)
{
  if (ws_size < WS_BYTES) return;
  char* ws = (char*)d_ws;

  const float* x       = (const float*)d_in[0];
  const float* w_down  = (const float*)d_in[1];
  const float* w_mid   = (const float*)d_in[2];
  const float* w_up    = (const float*)d_in[3];
  const float* wq_l    = (const float*)d_in[4];
  const float* wk_m    = (const float*)d_in[5];
  const float* wv_m    = (const float*)d_in[6];
  const float* wq_h    = (const float*)d_in[7];
  const float* rescale = (const float*)d_in[8];
  const float* w_proj_l= (const float*)d_in[9];
  const float* b_proj_l= (const float*)d_in[10];
  const float* w_proj_h= (const float*)d_in[11];
  const float* b_proj_h= (const float*)d_in[12];
  const float* qco_w1  = (const float*)d_in[13];
  const float* qsca_w  = (const float*)d_in[14];
  const float* qsca_b  = (const float*)d_in[15];
  const float* qt1_w   = (const float*)d_in[16];
  const float* qt1_b   = (const float*)d_in[17];
  const float* qt2_w   = (const float*)d_in[18];
  const float* qt2_b   = (const float*)d_in[19];
  const float* rsp_w1  = (const float*)d_in[20];
  const float* rsp_pr  = (const float*)d_in[21];
  const float* rsp_w2  = (const float*)d_in[22];
  const float* c31_w1  = (const float*)d_in[23];
  const float* c31_pr  = (const float*)d_in[24];
  const float* c31_w2  = (const float*)d_in[25];
  const float* c31_w3  = (const float*)d_in[26];
  const float* ln1_g   = (const float*)d_in[27];
  const float* ln1_b   = (const float*)d_in[28];
  const float* ff1_w1  = (const float*)d_in[29];
  const float* ff1_b1  = (const float*)d_in[30];
  const float* ff1_w2  = (const float*)d_in[31];
  const float* ff1_b2  = (const float*)d_in[32];
  const float* ln2_g   = (const float*)d_in[33];
  const float* ln2_b   = (const float*)d_in[34];
  const float* ff2_w1  = (const float*)d_in[35];
  const float* ff2_b1  = (const float*)d_in[36];
  const float* ff2_w2  = (const float*)d_in[37];
  const float* ff2_b2  = (const float*)d_in[38];

  bf16*  zbf   = (bf16*)(ws + OFF_ZBF);
  bf16*  wtq   = (bf16*)(ws + OFF_WTQ);
  bf16*  wtr1  = (bf16*)(ws + OFF_WTR1);
  bf16*  wtr2  = (bf16*)(ws + OFF_WTR2);
  bf16*  wtc1  = (bf16*)(ws + OFF_WTC1);
  bf16*  wtf   = (bf16*)(ws + OFF_WTF);
  float* w1t   = (float*)(ws + OFF_W1T);
  float* scawt = (float*)(ws + OFF_SCAWT);
  float* t1wt  = (float*)(ws + OFF_T1WT);
  float* t2wt  = (float*)(ws + OFF_T2WT);
  bf16*  Gb    = (bf16*)(ws + OFF_GB);
  bf16*  wqlb  = (bf16*)(ws + OFF_WQLB);
  bf16*  wkmb  = (bf16*)(ws + OFF_WKMB);
  bf16*  wqhb  = (bf16*)(ws + OFF_WQHB);
  float* gpart = (float*)(ws + OFF_GPART);
  float* T1    = (float*)(ws + OFF_T1);
  float* UL    = (float*)(ws + OFF_UL);
  float* UK    = (float*)(ws + OFF_UK);
  float* T1H   = (float*)(ws + OFF_T1H);
  float* UH    = (float*)(ws + OFF_UH);
  float* WeL   = (float*)(ws + OFF_WEL);
  float* WeH   = (float*)(ws + OFF_WEH);
  bf16*  acatb = (bf16*)(ws + OFF_ACATB);
  float* tsum  = (float*)(ws + OFF_TSUM);
  float* attb  = (float*)(ws + OFF_ATTB);
  short* hcatT = (short*)(ws + OFF_HCATT);
  short* midb  = (short*)(ws + OFF_MIDB);
  short* houtb = (short*)(ws + OFF_HOUTB);
  bf16*  wffb  = (bf16*)(ws + OFF_WFFB);
  short* xt    = (short*)(ws + OFF_XT);

  // 0) prep: all weight transforms + x transpose, one launch (3552 blocks)
  k_prep_all<<<dim3(3552), 256, 0, stream>>>(
      w_down, w_mid, w_up, rsp_w1, rsp_w2, c31_w1, wq_l, wk_m, wq_h,
      c31_w3, c31_w2, qco_w1, qsca_w, qt1_w, qt2_w,
      ff1_w1, ff1_w2, ff2_w1, ff2_w2, x,
      wtq, wtr1, wtr2, wtc1, wqlb, wkmb, wqhb, wtf,
      w1t, scawt, t1wt, t2wt, wffb, xt);

  // 1) fused QKV conv 64->384 -> Z (NCHW bf16), 192 oc/block, coalesced out
  k_convq<<<dim3(128, 2, 2), 256, 0, stream>>>(xt, (const short*)wtq, zbf);

  // 2) Gram (18 pairs x 16 k-chunks, XCD-grouped swizzle, 576 blocks)
  k_gramm<<<dim3(576), 256, 0, stream>>>((const short*)zbf, gpart);

  // 2b) merged: Gram reduce -> bf16 Gb | QCO tap sums (1280 blocks)
  k_gt<<<dim3(1280), 256, 0, stream>>>(gpart, Gb, zbf, tsum);

  // 3) MFMA solve chain on Gram blocks (5 jobs, symmetric-G B-operand)
  MJobs5 M5;
  M5.A[0] = (const short*)wqlb; M5.lda[0] = 64;  M5.K[0] = 64;  M5.r0[0] = 0;   M5.c0[0] = 64;  M5.C[0] = T1;  M5.ldc[0] = 128; M5.sC[0] = 32768;  M5.nx[0] = 2;
  M5.A[1] = (const short*)wqlb; M5.lda[1] = 64;  M5.K[1] = 64;  M5.r0[1] = 0;   M5.c0[1] = 0;   M5.C[1] = UL;  M5.ldc[1] = 64;  M5.sC[1] = 16384;  M5.nx[1] = 1;
  M5.A[2] = (const short*)wkmb; M5.lda[2] = 128; M5.K[2] = 128; M5.r0[2] = 64;  M5.c0[2] = 64;  M5.C[2] = UK;  M5.ldc[2] = 128; M5.sC[2] = 65536;  M5.nx[2] = 2;
  M5.A[3] = (const short*)wqhb; M5.lda[3] = 192; M5.K[3] = 192; M5.r0[3] = 192; M5.c0[3] = 64;  M5.C[3] = T1H; M5.ldc[3] = 128; M5.sC[3] = 98304;  M5.nx[3] = 2;
  M5.A[4] = (const short*)wqhb; M5.lda[4] = 192; M5.K[4] = 192; M5.r0[4] = 192; M5.c0[4] = 192; M5.C[4] = UH;  M5.ldc[4] = 192; M5.sC[4] = 147456; M5.nx[4] = 3;
  M5.b0[0] = 0; M5.b0[1] = 8; M5.b0[2] = 12; M5.b0[3] = 28; M5.b0[4] = 52; M5.b0[5] = 88;
  k_mgemm5<<<dim3(88, 2), 256, 0, stream>>>(M5, (const short*)Gb);

  // 3b) merged attention (512-thread blocks, 4-row K reuse): norms + logits + softmax + Weff | QCO tail
  k_attnw<<<dim3(33, 2), 512, 0, stream>>>(
      T1, T1H, UL, UK, UH, wq_l, wk_m, wq_h, wv_m, rescale, WeL, WeH,
      tsum, w1t, scawt, qsca_b, t1wt, qt1_b, t2wt, qt2_b, attb);

  Jobs2 J2;
  J2.A[0] = w_proj_l; J2.B[0] = WeL; J2.K[0] = 256; J2.lda[0] = 256; J2.sB[0] = 32768; J2.nx[0] = 8; J2.co[0] = 0;
  J2.A[1] = w_proj_h; J2.B[1] = WeH; J2.K[1] = 768; J2.lda[1] = 768; J2.sB[1] = 98304; J2.nx[1] = 8; J2.co[1] = 8192;
  J2.b0[0] = 0; J2.b0[1] = 32; J2.b0[2] = 128;
  k_sgemm2b<<<dim3(128, 2), 256, 0, stream>>>(J2, acatb);

  // 4) per-pixel linear map -> hcatT DIRECT (view-quirk transpose folded in)
  k_pixm<<<dim3(256, 4, 2), 256, 0, stream>>>((const short*)zbf, (const short*)acatb,
                                              b_proj_l, b_proj_h, hcatT);

  // 5) ReshapeBlock: 256->64 (+prelu) then 64->64
  k_conv64<1><<<dim3(128, 2, 2), 256, 0, stream>>>(
      hcatT, 256, 4194304L, 256, (const short*)wtr1, midb, rsp_pr);
  k_conv64<0><<<dim3(128, 2, 2), 256, 0, stream>>>(
      midb, 64, 1048576L, 64, (const short*)wtr2, houtb, nullptr);

  // 7) Conv3_1 first conv (+prelu)
  k_conv64<1><<<dim3(128, 2, 2), 256, 0, stream>>>(
      houtb, 64, 1048576L, 64, (const short*)wtc1, midb, c31_pr);

  // 7b+8) fused: folded conv + combine + double-FF -> d_out (NCHW f32)
  k_convff<<<dim3(128, 2, 2), 256, 0, stream>>>(
      midb, (const short*)wtf, houtb, attb, x, (const short*)wffb,
      ln1_g, ln1_b, ff1_b1, ff1_b2, ln2_g, ln2_b, ff2_b1, ff2_b2,
      (float*)d_out);
}

// Round 24
// 228.346 us; speedup vs baseline: 1.0760x; 1.0760x over previous
//
#include <hip/hip_runtime.h>
#include <hip/hip_bf16.h>
#include <stdint.h>

typedef __hip_bfloat16 bf16;
typedef __attribute__((ext_vector_type(8))) __bf16 bf8v;
typedef __attribute__((ext_vector_type(8))) short short8;
typedef __attribute__((ext_vector_type(4))) short short4v;
typedef __attribute__((ext_vector_type(4))) float f32x4;
#define DEVINL __device__ __forceinline__
#define MFMA16(a,b,c) __builtin_amdgcn_mfma_f32_16x16x32_bf16((a),(b),(c),0,0,0)

DEVINL short f2bs(float f) { bf16 h = __float2bfloat16(f); return *reinterpret_cast<short*>(&h); }
DEVINL float bs2f(short s) { bf16 h = *reinterpret_cast<bf16*>(&s); return __bfloat162float(h); }

// ---------------- problem dims ----------------
// B=2, C=64, H=W=128, n=16384, HEADS=8, DH=32. All device I/O buffers are f32.

// ---------------- workspace layout (BYTE offsets) ----------------
static const size_t OFF_ZBF   = 0;          // [2][384][16384] bf16 (QKV conv out, NCHW)
static const size_t OFF_WTQ   = 29360128;   // [9][384][64] bf16
static const size_t OFF_WTR1  = 29802496;   // [9][64][256] bf16
static const size_t OFF_WTR2  = 30097408;   // [9][64][64] bf16
static const size_t OFF_WTC1  = 30171136;   // [9][64][64] bf16
static const size_t OFF_WTF   = 30244864;   // [9][64][64] bf16 (folded c31 w3@w2)
static const size_t OFF_W1T   = 30318592;   // [576][64] f32 (qco_w1 transposed)
static const size_t OFF_SCAWT = 30466048;   // [64][64] f32
static const size_t OFF_T1WT  = 30482432;   // [128][64] f32
static const size_t OFF_T2WT  = 30515200;   // [64][64] f32
static const size_t OFF_GB    = 31645696;   // [2][384][384] bf16 (Gram, symmetric)
static const size_t OFF_WQLB  = 32235520;   // [256][64] bf16
static const size_t OFF_WKMB  = 32268288;   // [512][128] bf16
static const size_t OFF_WQHB  = 32399360;   // [768][192] bf16
static const size_t OFF_T1    = 41082880;   // [2][256][128] f32
static const size_t OFF_UL    = 41345024;   // [2][256][64] f32
static const size_t OFF_UK    = 41476096;   // [2][512][128] f32
static const size_t OFF_T1H   = 42000384;   // [2][768][128] f32
static const size_t OFF_UH    = 42786816;   // [2][768][192] f32
static const size_t OFF_WEL   = 44503040;   // [2][256][128] f32
static const size_t OFF_WEH   = 44765184;   // [2][768][128] f32
static const size_t OFF_ACATB = 45813760;   // [2][256][128] bf16
static const size_t OFF_TSUM  = 45944832;   // [2][64][9] f32
static const size_t OFF_ATTB  = 45949440;   // [2][64] f32
static const size_t OFF_HCATB = 45949952;   // [2][4194304] bf16 (view-quirk LINEAR layout)
static const size_t OFF_MIDB  = 62727168;   // [2][16384][64] bf16 (px-major)
static const size_t OFF_HOUTB = 66921472;   // [2][16384][64] bf16 (px-major)
static const size_t OFF_WFFB  = 71115776;   // [4][64][64] bf16 (FF weights)
static const size_t OFF_GPART = 79504384;   // [16][2][384][384] f32 ; ALSO (later) hcatT
static const size_t OFF_HCATT = 79504384;   // [2][16384][256] bf16 (aliases GPART, dead by then)
static const size_t OFF_XT    = 98378752;   // [2][16384][64] bf16 (x transposed)
static const size_t WS_BYTES  = 102573056;

// ================= prep (weight transforms + x transpose, one launch) =================
__global__ __launch_bounds__(256) void k_prep_all(
    const float* __restrict__ wd, const float* __restrict__ wm,
    const float* __restrict__ wu, const float* __restrict__ rw1,
    const float* __restrict__ rw2, const float* __restrict__ cw1,
    const float* __restrict__ wql, const float* __restrict__ wkm,
    const float* __restrict__ wqh,
    const float* __restrict__ c31w3, const float* __restrict__ c31w2,
    const float* __restrict__ qw1, const float* __restrict__ qscaw,
    const float* __restrict__ qt1w, const float* __restrict__ qt2w,
    const float* __restrict__ f11, const float* __restrict__ f12,
    const float* __restrict__ f21, const float* __restrict__ f22,
    const float* __restrict__ x,
    bf16* __restrict__ wtq, bf16* __restrict__ wtr1,
    bf16* __restrict__ wtr2, bf16* __restrict__ wtc1,
    bf16* __restrict__ wqlb, bf16* __restrict__ wkmb,
    bf16* __restrict__ wqhb, bf16* __restrict__ wtf,
    float* __restrict__ w1t, float* __restrict__ scawt,
    float* __restrict__ t1wt, float* __restrict__ t2wt,
    bf16* __restrict__ wffb, short* __restrict__ xt) {
  __shared__ short sT[64][72];
  const int t = threadIdx.x;
  if (blockIdx.x >= 3040) {
    // ---- x [b][64][16384] f32 -> xt [b][16384][64] bf16 ----
    const int j = blockIdx.x - 3040;           // 0..511
    const int b = j >> 8, p0 = (j & 255) * 64;
    for (int i = t; i < 1024; i += 256) {
      int c = i >> 4, p4 = (i & 15) * 4;
      float4 g = *(const float4*)&x[(((size_t)(b * 64 + c)) << 14) + p0 + p4];
      sT[p4 + 0][c] = f2bs(g.x);
      sT[p4 + 1][c] = f2bs(g.y);
      sT[p4 + 2][c] = f2bs(g.z);
      sT[p4 + 3][c] = f2bs(g.w);
    }
    __syncthreads();
    for (int i = t; i < 512; i += 256) {
      int p = i >> 3, co = (i & 7) * 8;
      *(short8*)&xt[((((size_t)b << 14) + p0 + p)) * 64 + co] = *(short8*)&sT[p][co];
    }
    return;
  }
  int i = blockIdx.x * 256 + t;
  if (i < 221184) {
    int tap = i / 24576, r = i % 24576, oc = r >> 6, ic = r & 63;
    float v;
    if (oc < 64)       v = wd[(oc * 64 + ic) * 9 + tap];
    else if (oc < 192) v = wm[((oc - 64) * 64 + ic) * 9 + tap];
    else               v = wu[((oc - 192) * 64 + ic) * 9 + tap];
    wtq[i] = __float2bfloat16(v);
  } else if (i < 368640) {
    int j = i - 221184;
    int tap = j / 16384, r = j % 16384, oc = r >> 8, ic = r & 255;
    wtr1[j] = __float2bfloat16(rw1[(oc * 256 + ic) * 9 + tap]);
  } else if (i < 405504) {
    int j = i - 368640;
    int tap = j / 4096, r = j % 4096, oc = r >> 6, ic = r & 63;
    wtr2[j] = __float2bfloat16(rw2[(oc * 64 + ic) * 9 + tap]);
  } else if (i < 442368) {
    int j = i - 405504;
    int tap = j / 4096, r = j % 4096, oc = r >> 6, ic = r & 63;
    wtc1[j] = __float2bfloat16(cw1[(oc * 64 + ic) * 9 + tap]);
  } else if (i < 458752) {
    int j = i - 442368; wqlb[j] = __float2bfloat16(wql[j]);
  } else if (i < 524288) {
    int j = i - 458752; wkmb[j] = __float2bfloat16(wkm[j]);
  } else if (i < 671744) {
    int j = i - 524288; wqhb[j] = __float2bfloat16(wqh[j]);
  } else if (i < 708608) {
    int j = i - 671744;
    int tap = j / 4096, r = j % 4096, o = r >> 6, ic = r & 63;
    float s = 0.f;
    for (int m = 0; m < 64; m++)
      s = fmaf(c31w3[o * 64 + m], c31w2[(m * 64 + ic) * 9 + tap], s);
    wtf[j] = __float2bfloat16(s);
  } else if (i < 745472) {
    int o = i - 708608;
    int c = o & 63, rest = o >> 6, jj = rest / 9, tap = rest % 9;
    w1t[o] = qw1[(c * 64 + jj) * 9 + tap];
  } else if (i < 749568) {
    int o = i - 745472;
    int c = o & 63, jj = o >> 6;
    scawt[o] = qscaw[c * 64 + jj];
  } else if (i < 757760) {
    int o = i - 749568;
    int c = o & 63, jj = o >> 6;
    t1wt[o] = qt1w[c * 128 + jj];
  } else if (i < 761856) {
    int o = i - 757760;
    int c = o & 63, jj = o >> 6;
    t2wt[o] = qt2w[c * 64 + jj];
  } else if (i < 778240) {
    int j = i - 761856;
    int stage = j >> 12, r = j & 4095;
    const float* src = (stage == 0) ? f11 : (stage == 1) ? f12 : (stage == 2) ? f21 : f22;
    wffb[j] = __float2bfloat16(src[r]);
  }
}

// hcat LINEAR (quirk view = NCHW [b][256][16384]) bf16 -> hcatT [b][16384][256] bf16
__global__ __launch_bounds__(256) void k_transph(const short* __restrict__ hc,
                                                 short* __restrict__ ht) {
  __shared__ short sT[64][72];
  const int t = threadIdx.x, b = blockIdx.z, p0 = blockIdx.x * 64, c0 = blockIdx.y * 64;
  for (int i = t; i < 512; i += 256) {
    int c = i >> 3, qo = (i & 7) * 8;
    short8 v = *(const short8*)&hc[(((size_t)(b * 256 + c0 + c)) << 14) + p0 + qo];
#pragma unroll
    for (int u = 0; u < 8; u++) sT[qo + u][c] = v[u];
  }
  __syncthreads();
  for (int i = t; i < 512; i += 256) {
    int q = i >> 3, co = (i & 7) * 8;
    *(short8*)&ht[((size_t)(b * 16384 + p0 + q)) * 256 + c0 + co] = *(short8*)&sT[q][co];
  }
}

// ========= QKV conv 64->384 (zero pad), direct-A MFMA, 192 oc/block, coalesced out ====
__global__ __launch_bounds__(256) void k_convq(
    const short* __restrict__ xt, const short* __restrict__ wtq,
    bf16* __restrict__ zbf)
{
  __shared__ short sX[3][130][72];   // 28080 shorts; reused as 192x132 output staging
  const int t = threadIdx.x, lane = t & 63, wv = t >> 6;
  const int y = blockIdx.x, ocg = blockIdx.y, b = blockIdx.z;

  for (int i = t; i < 3120; i += 256) {
    int ko = i & 7, c2 = i >> 3, col = c2 % 130, row = c2 / 130;
    int gy = y + row - 1, gx = col - 1;
    short8 vv;
    if ((gy >= 0) & (gy < 128) & (gx >= 0) & (gx < 128)) {
      vv = *(const short8*)&xt[((size_t)b * 1048576 + (size_t)((gy << 7) + gx) * 64) + ko * 8];
    } else {
#pragma unroll
      for (int u = 0; u < 8; u++) vv[u] = 0;
    }
    *(short8*)&sX[row][col][ko * 8] = vv;
  }
  __syncthreads();

  const f32x4 zero = {0.f, 0.f, 0.f, 0.f};
  f32x4 acc[3][8];
#pragma unroll
  for (int m = 0; m < 3; m++)
#pragma unroll
    for (int n = 0; n < 8; n++) acc[m][n] = zero;

#pragma unroll
  for (int tap = 0; tap < 9; tap++) {
    const int ky = tap / 3, kx = tap % 3;
#pragma unroll
    for (int kk = 0; kk < 2; kk++) {
      const int kb = kk * 32 + (lane >> 4) * 8;
      bf8v a0 = *(const bf8v*)&wtq[(size_t)((tap * 384 + ocg * 192 + wv * 48 + (lane & 15)) * 64) + kb];
      bf8v a1 = *(const bf8v*)&wtq[(size_t)((tap * 384 + ocg * 192 + wv * 48 + 16 + (lane & 15)) * 64) + kb];
      bf8v a2 = *(const bf8v*)&wtq[(size_t)((tap * 384 + ocg * 192 + wv * 48 + 32 + (lane & 15)) * 64) + kb];
#pragma unroll
      for (int n = 0; n < 8; n++) {
        bf8v bfr = *(const bf8v*)&sX[ky][n * 16 + (lane & 15) + kx][kb];
        acc[0][n] = MFMA16(a0, bfr, acc[0][n]);
        acc[1][n] = MFMA16(a1, bfr, acc[1][n]);
        acc[2][n] = MFMA16(a2, bfr, acc[2][n]);
      }
    }
  }
  // epilogue: stage [192 oc][128 px] bf16 tile in LDS, write coalesced 256B rows
  __syncthreads();
  short* sO = &sX[0][0][0];   // needs 192*132 = 25344 shorts <= 28080
#pragma unroll
  for (int m = 0; m < 3; m++) {
    const int ocl = wv * 48 + m * 16 + ((lane >> 4) << 2);
#pragma unroll
    for (int n = 0; n < 8; n++) {
      const int px = n * 16 + (lane & 15);
      sO[(ocl + 0) * 132 + px] = f2bs(acc[m][n][0]);
      sO[(ocl + 1) * 132 + px] = f2bs(acc[m][n][1]);
      sO[(ocl + 2) * 132 + px] = f2bs(acc[m][n][2]);
      sO[(ocl + 3) * 132 + px] = f2bs(acc[m][n][3]);
    }
  }
  __syncthreads();
  for (int i = t; i < 3072; i += 256) {
    int ocl = i >> 4, px8 = (i & 15) * 8;
    *(short8*)&zbf[(((size_t)(b * 384 + ocg * 192 + ocl)) << 14) + (y << 7) + px8] =
        *(short8*)&sO[ocl * 132 + px8];
  }
}

// ================= 3x3 reflect conv -> 64 out (direct-A MFMA, px-major IO) =================
template<int EPI>
__global__ __launch_bounds__(256) void k_conv64(
    const short* __restrict__ in, int str, long bstride, int Cin,
    const short* __restrict__ Wt,
    short* __restrict__ outb,
    const float* __restrict__ prelu_a)
{
  __shared__ short sX[3][66][72];
  const int t = threadIdx.x, lane = t & 63, wv = t >> 6;
  const int y = blockIdx.x, x0 = blockIdx.y * 64, b = blockIdx.z;

  const f32x4 zero = {0.f, 0.f, 0.f, 0.f};
  f32x4 acc[4] = {zero, zero, zero, zero};

  for (int icb = 0; icb < Cin; icb += 64) {
    __syncthreads();
    for (int i = t; i < 1584; i += 256) {
      int ko = i & 7, c2 = i >> 3, col = c2 % 66, row = c2 / 66;
      int gy = y + row - 1, gx = x0 + col - 1;
      gy = gy < 0 ? 1 : (gy > 127 ? 126 : gy);
      gx = gx < 0 ? 1 : (gx > 127 ? 126 : gx);
      *(short8*)&sX[row][col][ko * 8] =
          *(const short8*)&in[(size_t)b * bstride + (size_t)((gy << 7) + gx) * str + icb + ko * 8];
    }
    __syncthreads();
#pragma unroll
    for (int tap = 0; tap < 9; tap++) {
      const int ky = tap / 3, kx = tap % 3;
#pragma unroll
      for (int kk = 0; kk < 2; kk++) {
        const int kb = kk * 32 + (lane >> 4) * 8;
        bf8v afr = *(const bf8v*)&Wt[(size_t)(tap * 64 + wv * 16 + (lane & 15)) * Cin + icb + kb];
#pragma unroll
        for (int n = 0; n < 4; n++) {
          bf8v bfr = *(const bf8v*)&sX[ky][n * 16 + (lane & 15) + kx][kb];
          acc[n] = MFMA16(afr, bfr, acc[n]);
        }
      }
    }
  }
  const int oc0 = wv * 16 + ((lane >> 4) << 2);
  const float aP = (EPI == 1) ? prelu_a[0] : 0.f;
#pragma unroll
  for (int n = 0; n < 4; n++) {
    const int gpx = (y << 7) + x0 + n * 16 + (lane & 15);
    short4v ss;
#pragma unroll
    for (int r = 0; r < 4; r++) {
      float v = acc[n][r];
      if (EPI == 1) v = v > 0.f ? v : aP * v;
      ss[r] = f2bs(v);
    }
    *(short4v*)&outb[((size_t)(b * 16384 + gpx)) * 64 + oc0] = ss;
  }
}

// ======= fused final conv (folded c31_w2@w3) + combine + double-FF -> d_out =======
__global__ __launch_bounds__(256) void k_convff(
    const short* __restrict__ in,
    const short* __restrict__ Wt,
    const short* __restrict__ houtpm,
    const float* __restrict__ attb,
    const float* __restrict__ x_nchw,
    const short* __restrict__ wffb,
    const float* __restrict__ g1, const float* __restrict__ be1,
    const float* __restrict__ b11, const float* __restrict__ b12,
    const float* __restrict__ g2, const float* __restrict__ be2,
    const float* __restrict__ b21, const float* __restrict__ b22,
    float* __restrict__ outp)
{
  __shared__ short sX[3][66][72];
  __shared__ float sv[64][68];
  __shared__ short sy[64][72];
  __shared__ float spar[8][64];
  const int t = threadIdx.x, lane = t & 63, wv = t >> 6;
  const int y = blockIdx.x, x0 = blockIdx.y * 64, b = blockIdx.z;

  if (t < 64) {
    spar[0][t] = g1[t]; spar[1][t] = be1[t]; spar[2][t] = b11[t]; spar[3][t] = b12[t];
    spar[4][t] = g2[t]; spar[5][t] = be2[t]; spar[6][t] = b21[t]; spar[7][t] = b22[t];
  }
  for (int i = t; i < 1584; i += 256) {
    int ko = i & 7, c2 = i >> 3, col = c2 % 66, row = c2 / 66;
    int gy = y + row - 1, gx = x0 + col - 1;
    gy = gy < 0 ? 1 : (gy > 127 ? 126 : gy);
    gx = gx < 0 ? 1 : (gx > 127 ? 126 : gx);
    *(short8*)&sX[row][col][ko * 8] =
        *(const short8*)&in[(size_t)b * 1048576 + (size_t)((gy << 7) + gx) * 64 + ko * 8];
  }
  __syncthreads();

  const f32x4 zero = {0.f, 0.f, 0.f, 0.f};
  {
    f32x4 cacc[4] = {zero, zero, zero, zero};
#pragma unroll
    for (int tap = 0; tap < 9; tap++) {
      const int ky = tap / 3, kx = tap % 3;
#pragma unroll
      for (int kk = 0; kk < 2; kk++) {
        const int kb = kk * 32 + (lane >> 4) * 8;
        bf8v afr = *(const bf8v*)&Wt[(size_t)(tap * 64 + wv * 16 + (lane & 15)) * 64 + kb];
#pragma unroll
        for (int n = 0; n < 4; n++) {
          bf8v bfr = *(const bf8v*)&sX[ky][n * 16 + (lane & 15) + kx][kb];
          cacc[n] = MFMA16(afr, bfr, cacc[n]);
        }
      }
    }
    const int oc0 = wv * 16 + ((lane >> 4) << 2);
    float4 av = *(const float4*)&attb[b * 64 + oc0];
#pragma unroll
    for (int n = 0; n < 4; n++) {
      const int pxl = n * 16 + (lane & 15);
      const int gpx = (y << 7) + x0 + pxl;
      short4v hv = *(const short4v*)&houtpm[((size_t)(b * 16384 + gpx)) * 64 + oc0];
#pragma unroll
      for (int r = 0; r < 4; r++)
        sv[pxl][oc0 + r] = cacc[n][r] + bs2f(hv[r]) * (&av.x)[r] +
                           x_nchw[(((size_t)(b * 64 + oc0 + r)) << 14) + gpx];
    }
  }
  __syncthreads();

  const int chq = ((lane >> 4) << 2);
  const int pxl = wv * 16 + (lane & 15);
  float4 vv[4];
#pragma unroll
  for (int m = 0; m < 4; m++) vv[m] = *(const float4*)&sv[pxl][m * 16 + chq];

  f32x4 facc[4];

#define LN_F(SRCV, GI, BI)                                                      \
  {                                                                             \
    float s1 = 0.f, s2 = 0.f;                                                   \
    _Pragma("unroll")                                                           \
    for (int m = 0; m < 4; m++)                                                 \
      _Pragma("unroll")                                                         \
      for (int r = 0; r < 4; r++) {                                             \
        float vx = (&SRCV[m].x)[r];                                             \
        s1 += vx; s2 += vx * vx;                                                \
      }                                                                         \
    s1 += __shfl_xor(s1, 16); s1 += __shfl_xor(s1, 32);                         \
    s2 += __shfl_xor(s2, 16); s2 += __shfl_xor(s2, 32);                         \
    float mu = s1 * (1.f / 64.f);                                               \
    float var = fmaxf(s2 * (1.f / 64.f) - mu * mu, 0.f);                        \
    float rstd = 1.f / sqrtf(var + 1e-5f);                                      \
    _Pragma("unroll")                                                           \
    for (int m = 0; m < 4; m++) {                                               \
      short4v ss;                                                               \
      _Pragma("unroll")                                                         \
      for (int r = 0; r < 4; r++) {                                             \
        int ch = m * 16 + chq + r;                                              \
        ss[r] = f2bs(((&SRCV[m].x)[r] - mu) * rstd * spar[GI][ch] + spar[BI][ch]); \
      }                                                                         \
      *(short4v*)&sy[pxl][m * 16 + chq] = ss;                                   \
    }                                                                           \
  }

#define MM_F(SIDX)                                                              \
  {                                                                             \
    _Pragma("unroll")                                                           \
    for (int m = 0; m < 4; m++) facc[m] = zero;                                 \
    _Pragma("unroll")                                                           \
    for (int kk = 0; kk < 2; kk++) {                                            \
      const int kb = kk * 32 + (lane >> 4) * 8;                                 \
      bf8v bfr = *(const bf8v*)&sy[wv * 16 + (lane & 15)][kb];                  \
      _Pragma("unroll")                                                         \
      for (int m = 0; m < 4; m++) {                                             \
        bf8v afr = *(const bf8v*)&wffb[(size_t)(SIDX) * 4096 +                  \
                                       (m * 16 + (lane & 15)) * 64 + kb];       \
        facc[m] = MFMA16(afr, bfr, facc[m]);                                    \
      }                                                                         \
    }                                                                           \
  }

  LN_F(vv, 0, 1);
  MM_F(0);
#pragma unroll
  for (int m = 0; m < 4; m++) {
    short4v ss;
#pragma unroll
    for (int r = 0; r < 4; r++) {
      float h = facc[m][r] + spar[2][m * 16 + chq + r];
      h = h > 0.f ? h : 0.01f * h;
      ss[r] = f2bs(h);
    }
    *(short4v*)&sy[pxl][m * 16 + chq] = ss;
  }
  MM_F(1);
  float4 o2v[4];
#pragma unroll
  for (int m = 0; m < 4; m++)
#pragma unroll
    for (int r = 0; r < 4; r++)
      (&o2v[m].x)[r] = facc[m][r] + spar[3][m * 16 + chq + r] + (&vv[m].x)[r];
  LN_F(o2v, 4, 5);
  MM_F(2);
#pragma unroll
  for (int m = 0; m < 4; m++) {
    short4v ss;
#pragma unroll
    for (int r = 0; r < 4; r++) {
      float h = facc[m][r] + spar[6][m * 16 + chq + r];
      h = h > 0.f ? h : 0.01f * h;
      ss[r] = f2bs(h);
    }
    *(short4v*)&sy[pxl][m * 16 + chq] = ss;
  }
  MM_F(3);
  const int gpx = (y << 7) + x0 + pxl;
#pragma unroll
  for (int m = 0; m < 4; m++)
#pragma unroll
    for (int r = 0; r < 4; r++) {
      const int ch = m * 16 + chq + r;
      outp[(((size_t)(b * 64 + ch)) << 14) + gpx] =
          facc[m][r] + spar[7][ch] + (&vv[m].x)[r];
    }
#undef LN_F
#undef MM_F
}

// ======= Gram via MFMA: G[b] = Z Z^T (18 needed pairs x 16 k-chunks of 1024) =======
// XCD-grouped swizzle: all 18 pair-blocks of one (kc,b) group land on one XCD slot
__global__ __launch_bounds__(256) void k_gramm(const short* __restrict__ Z,
                                               float* __restrict__ Gp) {
  static const char TIa[18] = {0,0,0,1,1,2,1,1,1,2,2,2,3,3,3,4,4,5};
  static const char TJa[18] = {0,1,2,1,2,2,3,4,5,3,4,5,3,4,5,4,5,5};
  const int L = blockIdx.x;
  const int xcd = L & 7;
  const int rest = L >> 3;
  const int p = rest % 18;
  const int ghi = rest / 18;
  const int g = xcd + 8 * ghi;        // 0..31
  const int kc = g & 15, b = g >> 4;
  const int ti = TIa[p], tj = TJa[p];
  const bool diag = (ti == tj);
  __shared__ short sA[64][72];
  __shared__ short sB[64][72];
  short (*sBp)[72] = diag ? sA : sB;
  const int t = threadIdx.x, lane = t & 63, wv = t >> 6;
  const int wo = wv & 1, wp = wv >> 1;
  const f32x4 zero = {0.f, 0.f, 0.f, 0.f};
  f32x4 acc[2][2];
#pragma unroll
  for (int m = 0; m < 2; m++)
#pragma unroll
    for (int n = 0; n < 2; n++) acc[m][n] = zero;
  const size_t zb = (size_t)b * 6291456;
  const int k0 = kc * 1024;
  for (int ks = 0; ks < 1024; ks += 64) {
    __syncthreads();
    for (int i = t; i < 512; i += 256) {
      int r = i >> 3, ko = i & 7;
      *(short8*)&sA[r][ko * 8] =
          *(const short8*)&Z[zb + ((size_t)(ti * 64 + r) << 14) + k0 + ks + ko * 8];
      if (!diag)
        *(short8*)&sB[r][ko * 8] =
            *(const short8*)&Z[zb + ((size_t)(tj * 64 + r) << 14) + k0 + ks + ko * 8];
    }
    __syncthreads();
#pragma unroll
    for (int kk = 0; kk < 2; kk++) {
      const int kb = kk * 32 + (lane >> 4) * 8;
      bf8v bfr[2];
#pragma unroll
      for (int n = 0; n < 2; n++)
        bfr[n] = *(const bf8v*)&sBp[wp * 32 + n * 16 + (lane & 15)][kb];
#pragma unroll
      for (int m = 0; m < 2; m++) {
        bf8v afr = *(const bf8v*)&sA[wo * 32 + m * 16 + (lane & 15)][kb];
#pragma unroll
        for (int n = 0; n < 2; n++)
          acc[m][n] = MFMA16(afr, bfr[n], acc[m][n]);
      }
    }
  }
  float* gp = Gp + ((size_t)(kc * 2 + b)) * 147456;
#pragma unroll
  for (int m = 0; m < 2; m++)
#pragma unroll
    for (int n = 0; n < 2; n++)
#pragma unroll
      for (int r = 0; r < 4; r++) {
        const int row = ti * 64 + wo * 32 + m * 16 + ((lane >> 4) << 2) + r;
        const int col = tj * 64 + wp * 32 + n * 16 + (lane & 15);
        float v = acc[m][n][r];
        gp[(size_t)row * 384 + col] = v;
        if (ti != tj) gp[(size_t)col * 384 + row] = v;
      }
}

// ======= merged: reduce partials (16) -> bf16 Gb  |  QCO tap sums =======
__global__ __launch_bounds__(256) void k_gt(const float* __restrict__ Gp,
                                            bf16* __restrict__ Gb,
                                            const bf16* __restrict__ Z,
                                            float* __restrict__ Tsum) {
  __shared__ float sc[16];
  __shared__ float red[4][9];
  const int t = threadIdx.x;
  if (blockIdx.x < 1152) {
    int i = blockIdx.x * 256 + t;
    if (i >= 294912) return;
    int b = i / 147456, e = i % 147456;
    float s = 0.f;
#pragma unroll
    for (int c = 0; c < 16; c++) s += Gp[(size_t)(c * 2 + b) * 147456 + e];
    Gb[(size_t)b * 147456 + e] = __float2bfloat16(s);
    return;
  }
  const int bid = blockIdx.x - 1152;
  const int c = bid & 63, b = bid >> 6;
  const bf16* src = Z + (((size_t)(b * 384 + c)) << 14);
  float a9[9] = {};
  for (int i = t; i < 2048; i += 256) {
    int y = i >> 4, x0 = (i & 15) * 8;
    short8 v8 = *(const short8*)&src[(y << 7) + x0];
    float vs[8], s8 = 0.f;
#pragma unroll
    for (int u = 0; u < 8; u++) { vs[u] = bs2f(v8[u]); s8 += vs[u]; }
    a9[0] += s8;
    int ri = (y == 0) ? 0 : (y == 1) ? 1 : (y == 126) ? 2 : (y == 127) ? 3 : -1;
    if (ri >= 0) a9[1 + ri] += s8;
    if (x0 == 0)   { a9[5] += vs[0]; a9[6] += vs[1]; }
    if (x0 == 120) { a9[7] += vs[6]; a9[8] += vs[7]; }
    if (ri >= 0) {
      if (x0 == 0)   { sc[ri * 4 + 0] = vs[0]; sc[ri * 4 + 1] = vs[1]; }
      if (x0 == 120) { sc[ri * 4 + 2] = vs[6]; sc[ri * 4 + 3] = vs[7]; }
    }
  }
#pragma unroll
  for (int q = 0; q < 9; q++)
#pragma unroll
    for (int o = 32; o; o >>= 1) a9[q] += __shfl_xor(a9[q], o);
  const int w = t >> 6;
  if ((t & 63) == 0)
#pragma unroll
    for (int q = 0; q < 9; q++) red[w][q] = a9[q];
  __syncthreads();
  if (t == 0) {
    float s9[9];
#pragma unroll
    for (int q = 0; q < 9; q++) s9[q] = red[0][q] + red[1][q] + red[2][q] + red[3][q];
    const float T = s9[0];
    float R[4] = {s9[1], s9[2], s9[3], s9[4]};
    const float C0 = s9[5], C1 = s9[6], C126 = s9[7], C127 = s9[8];
    float rs[4][3];
#pragma unroll
    for (int ri = 0; ri < 4; ri++) {
      rs[ri][0] = R[ri] - sc[ri * 4 + 3] + sc[ri * 4 + 1];
      rs[ri][1] = R[ri];
      rs[ri][2] = R[ri] - sc[ri * 4 + 0] + sc[ri * 4 + 2];
    }
    float A3[3] = {T - C127 + C1, T, T - C0 + C126};
#pragma unroll
    for (int dx = 0; dx < 3; dx++) {
      Tsum[bid * 9 + 0 * 3 + dx] = A3[dx] - rs[3][dx] + rs[1][dx];
      Tsum[bid * 9 + 1 * 3 + dx] = A3[dx];
      Tsum[bid * 9 + 2 * 3 + dx] = A3[dx] - rs[0][dx] + rs[2][dx];
    }
  }
}

// ======= MFMA solve chain (5 jobs): C = W[M,K] * G[r0:r0+K, c0:c0+N] =======
struct MJobs5 {
  const short* A[5];
  float* C[5];
  int lda[5], K[5], r0[5], c0[5], ldc[5];
  long sC[5];
  int nx[5], b0[6];
};

__global__ __launch_bounds__(256) void k_mgemm5(MJobs5 J, const short* __restrict__ Gb) {
  const int bx = blockIdx.x, z = blockIdx.y;
  int j = 0;
  while (bx >= J.b0[j + 1]) j++;
  const int local = bx - J.b0[j];
  const int xn = local % J.nx[j], ym = local / J.nx[j];
  const int t = threadIdx.x, lane = t & 63, wv = t >> 6;
  const short* Gp = Gb + (size_t)z * 147456;
  const short* Ap = J.A[j];
  const int K = J.K[j], lda = J.lda[j];
  const int m0 = ym * 64 + wv * 16, n0 = xn * 64;
  const int gc0 = J.c0[j] + n0, r0 = J.r0[j];
  const f32x4 zero = {0.f, 0.f, 0.f, 0.f};
  f32x4 acc[4] = {zero, zero, zero, zero};
  for (int kk = 0; kk < K; kk += 32) {
    const int kb = kk + (lane >> 4) * 8;
    bf8v afr = *(const bf8v*)&Ap[(size_t)(m0 + (lane & 15)) * lda + kb];
#pragma unroll
    for (int n = 0; n < 4; n++) {
      bf8v bfr = *(const bf8v*)&Gp[(size_t)(gc0 + n * 16 + (lane & 15)) * 384 + r0 + kb];
      acc[n] = MFMA16(afr, bfr, acc[n]);
    }
  }
  float* Cp = J.C[j] + (size_t)z * J.sC[j];
  const int mq = m0 + ((lane >> 4) << 2);
#pragma unroll
  for (int n = 0; n < 4; n++) {
    const int nc = n0 + n * 16 + (lane & 15);
#pragma unroll
    for (int r = 0; r < 4; r++)
      Cp[(size_t)(mq + r) * J.ldc[j] + nc] = acc[n][r];
  }
}

// ================= per-pixel map via MFMA (view-quirk LINEAR output) =================
__global__ __launch_bounds__(256) void k_pixm(
    const short* __restrict__ Z, const short* __restrict__ Acatb,
    const float* __restrict__ bl, const float* __restrict__ bh,
    bf16* __restrict__ hcat)
{
  const int p0 = blockIdx.x * 64, ocg = blockIdx.y, b = blockIdx.z;
  __shared__ short sA[64][136];
  __shared__ short sB[64][136];
  const int t = threadIdx.x, lane = t & 63, wv = t >> 6;
  for (int i = t; i < 1024; i += 256) {
    int oc = i >> 4, ko = i & 15;
    *(short8*)&sA[oc][ko * 8] =
        *(const short8*)&Acatb[((size_t)(b * 256 + ocg * 64 + oc)) * 128 + ko * 8];
  }
  for (int i = t; i < 1024; i += 256) {
    int px = i & 63, ko = i >> 6;
    short8 vv;
#pragma unroll
    for (int u = 0; u < 8; u++)
      vv[u] = Z[((size_t)(b * 384 + 64 + ko * 8 + u) << 14) + p0 + px];
    *(short8*)&sB[px][ko * 8] = vv;
  }
  __syncthreads();
  const f32x4 zero = {0.f, 0.f, 0.f, 0.f};
  f32x4 acc[4] = {zero, zero, zero, zero};
#pragma unroll
  for (int kk = 0; kk < 4; kk++) {
    const int kb = kk * 32 + (lane >> 4) * 8;
    bf8v afr = *(const bf8v*)&sA[wv * 16 + (lane & 15)][kb];
#pragma unroll
    for (int n = 0; n < 4; n++) {
      bf8v bfr = *(const bf8v*)&sB[n * 16 + (lane & 15)][kb];
      acc[n] = MFMA16(afr, bfr, acc[n]);
    }
  }
  const size_t hbase = (size_t)b * 4194304;
#pragma unroll
  for (int n = 0; n < 4; n++) {
    const int px = p0 + n * 16 + (lane & 15);
#pragma unroll
    for (int r = 0; r < 4; r++) {
      const int oc = ocg * 64 + wv * 16 + ((lane >> 4) << 2) + r;
      float v = acc[n][r] + (oc < 64 ? bl[oc] : bh[oc - 64]);
      size_t addr = (oc < 64) ? hbase + (size_t)px * 64 + oc
                              : hbase + 1048576 + (size_t)px * 192 + (oc - 64);
      hcat[addr] = __float2bfloat16(v);
    }
  }
}

// ================= proj GEMMs (2 jobs) -> bf16 Acat =================
struct Jobs2 {
  const float* A[2]; const float* B[2];
  int K[2]; int lda[2];
  long sB[2];
  int nx[2]; int b0[3]; int co[2];
};

__global__ __launch_bounds__(256) void k_sgemm2b(Jobs2 J, bf16* __restrict__ Cb) {
  __shared__ float sa[16][17];
  __shared__ float sb[16][17];
  const int bx = blockIdx.x, z = blockIdx.y;
  int j = (bx >= J.b0[1]) ? 1 : 0;
  const int local = bx - J.b0[j];
  const int x = local % J.nx[j], y = local / J.nx[j];
  const int tx = threadIdx.x & 15, ty = threadIdx.x >> 4;
  const float* Ap = J.A[j];
  const float* Bp = J.B[j] + (size_t)z * J.sB[j];
  const int K = J.K[j], lda = J.lda[j];
  const int m = y * 16 + ty, n = x * 16 + tx;
  float acc = 0.f;
  for (int k0 = 0; k0 < K; k0 += 16) {
    sa[ty][tx] = Ap[(size_t)m * lda + k0 + tx];
    sb[ty][tx] = Bp[(size_t)(k0 + ty) * 128 + n];
    __syncthreads();
#pragma unroll
    for (int kk = 0; kk < 16; kk++) acc = fmaf(sa[ty][kk], sb[kk][tx], acc);
    __syncthreads();
  }
  Cb[(size_t)z * 32768 + J.co[j] + (size_t)m * 128 + n] = __float2bfloat16(acc);
}

// ======= merged attention (512 threads): float4 LDS dots, 4-row K reuse | QCO tail =======
// grid (33, 2): bx<32 -> attn block (h=bx>>2, cy=bx&3), bx==32 -> QCO tail (b=blockIdx.y)
__global__ __launch_bounds__(512) void k_attnw(
    const float* __restrict__ T1, const float* __restrict__ T1H,
    const float* __restrict__ UL, const float* __restrict__ UK,
    const float* __restrict__ UH,
    const float* __restrict__ wql, const float* __restrict__ wkm,
    const float* __restrict__ wqh, const float* __restrict__ wvm,
    const float* __restrict__ rescale,
    float* __restrict__ WeL, float* __restrict__ WeH,
    const float* __restrict__ Tsum, const float* __restrict__ w1t,
    const float* __restrict__ scawt, const float* __restrict__ scab,
    const float* __restrict__ t1wt, const float* __restrict__ t1b,
    const float* __restrict__ t2wt, const float* __restrict__ t2b,
    float* __restrict__ attb)
{
  __shared__ float sK[64 * 132];
  __shared__ float sQ[32 * 132];
  __shared__ float sAt[32 * 64];
  __shared__ float sNk[64];
  __shared__ float sNq[32];
  __shared__ float sm[64], sxq[64], scat[128], sh1[64];
  const int t = threadIdx.x, b = blockIdx.y;

  if (blockIdx.x == 32) {
    // ---- QCO tail; only t<64 computes, all threads hit barriers ----
    const int c = t;
    if (t < 64) {
      float acc = 0.f;
      for (int j = 0; j < 64; j++) {
#pragma unroll
        for (int tap = 0; tap < 9; tap++)
          acc = fmaf(w1t[((j * 9 + tap) << 6) + c], Tsum[(b * 64 + j) * 9 + tap], acc);
      }
      sm[c] = acc * (1.f / 16384.f);
    }
    __syncthreads();
    if (t < 64) {
      float xa = scab[c];
      for (int j = 0; j < 64; j++) xa = fmaf(scawt[(j << 6) + c], sm[j], xa);
      sxq[c] = xa;
    }
    __syncthreads();
    if (t < 64) {
      float xa = sxq[c];
      float mn = xa, mx = xa;
#pragma unroll
      for (int o = 32; o; o >>= 1) {
        mn = fminf(mn, __shfl_xor(mn, o));
        mx = fmaxf(mx, __shfl_xor(mx, o));
      }
      float inter = (mx - mn) * (1.f / 64.f);
      float ql = (2.f * c + 1.f) / 128.f * (mx - mn) + mn;
      float sta = 0.f;
      for (int j = 0; j < 64; j++) {
        float q = 1.f - fabsf(ql - sxq[j]);
        sta += (q > 1.f - inter) ? q : 0.f;
      }
      float tot = sta;
#pragma unroll
      for (int o = 32; o; o >>= 1) tot += __shfl_xor(tot, o);
      sta = sta / fmaxf(tot, 1e-30f);
      scat[c] = sta; scat[64 + c] = xa;
    }
    __syncthreads();
    if (t < 64) {
      float h = t1b[c];
      for (int j = 0; j < 128; j++) h = fmaf(t1wt[(j << 6) + c], scat[j], h);
      h = fmaxf(h, 0.f);
      sh1[c] = h;
    }
    __syncthreads();
    if (t < 64) {
      float o2 = t2b[c];
      for (int j = 0; j < 64; j++) o2 = fmaf(t2wt[(j << 6) + c], sh1[j], o2);
      attb[b * 64 + c] = fmaxf(o2, 0.f);
    }
    return;
  }

  const int h = blockIdx.x >> 2, cy = blockIdx.x & 3;
  const int isL = (cy == 0);
  const int rbase = isL ? 0 : (cy - 1) * 32;
  const float* TQ = isL ? (T1 + (size_t)(b * 256 + h * 32) * 128)
                        : (T1H + (size_t)(b * 768 + h * 96 + rbase) * 128);
  for (int idx = t; idx < 8192; idx += 512) {
    int e = idx >> 7, k = idx & 127;
    sK[e * 132 + k] = wkm[(size_t)(h * 64 + e) * 128 + k];
  }
  for (int idx = t; idx < 4096; idx += 512) {
    int r = idx >> 7, k = idx & 127;
    sQ[r * 132 + k] = TQ[(size_t)r * 128 + k];
  }
  __syncthreads();

  // inline norms: per-thread serial dots with float4 loads (same summation order)
  if (t < 64) {
    const float4* u4 = (const float4*)(UK + (size_t)(b * 512 + h * 64 + t) * 128);
    const float4* k4 = (const float4*)&sK[t * 132];
    float s = 0.f;
    for (int q = 0; q < 32; q++) {
      float4 a = u4[q], c = k4[q];
      s = fmaf(a.x, c.x, s); s = fmaf(a.y, c.y, s);
      s = fmaf(a.z, c.z, s); s = fmaf(a.w, c.w, s);
    }
    sNk[t] = fmaxf(sqrtf(fmaxf(s, 0.f)), 1e-12f);
  } else if (t >= 128 && t < 160) {
    const int r = t - 128;
    const float* u; const float* wv; int K;
    if (isL) { K = 64;  u = UL + (size_t)(b * 256 + h * 32 + r) * 64;
               wv = wql + (size_t)(h * 32 + r) * 64; }
    else     { K = 192; u = UH + (size_t)(b * 768 + h * 96 + rbase + r) * 192;
               wv = wqh + (size_t)(h * 96 + rbase + r) * 192; }
    const float4* u4 = (const float4*)u;
    const float4* w4 = (const float4*)wv;
    float s = 0.f;
    for (int q = 0; q < (K >> 2); q++) {
      float4 a = u4[q], c = w4[q];
      s = fmaf(a.x, c.x, s); s = fmaf(a.y, c.y, s);
      s = fmaf(a.z, c.z, s); s = fmaf(a.w, c.w, s);
    }
    sNq[r] = fmaxf(sqrtf(fmaxf(s, 0.f)), 1e-12f);
  }
  __syncthreads();

  const int w = t >> 6, lane = t & 63;   // 8 waves
  const float rs = rescale[h];
  {
    // 4 rows per wave (w, w+8, w+16, w+24), K row loaded once per q
    const float4* k4 = (const float4*)&sK[lane * 132];
    const float4* q40 = (const float4*)&sQ[(w)      * 132];
    const float4* q41 = (const float4*)&sQ[(w + 8)  * 132];
    const float4* q42 = (const float4*)&sQ[(w + 16) * 132];
    const float4* q43 = (const float4*)&sQ[(w + 24) * 132];
    float s0 = 0.f, s1 = 0.f, s2 = 0.f, s3 = 0.f;
#pragma unroll
    for (int q = 0; q < 32; q++) {
      float4 c = k4[q];
      float4 a;
      a = q40[q]; s0 = fmaf(a.x, c.x, s0); s0 = fmaf(a.y, c.y, s0);
                  s0 = fmaf(a.z, c.z, s0); s0 = fmaf(a.w, c.w, s0);
      a = q41[q]; s1 = fmaf(a.x, c.x, s1); s1 = fmaf(a.y, c.y, s1);
                  s1 = fmaf(a.z, c.z, s1); s1 = fmaf(a.w, c.w, s1);
      a = q42[q]; s2 = fmaf(a.x, c.x, s2); s2 = fmaf(a.y, c.y, s2);
                  s2 = fmaf(a.z, c.z, s2); s2 = fmaf(a.w, c.w, s2);
      a = q43[q]; s3 = fmaf(a.x, c.x, s3); s3 = fmaf(a.y, c.y, s3);
                  s3 = fmaf(a.z, c.z, s3); s3 = fmaf(a.w, c.w, s3);
    }
    float ss[4] = {s0, s1, s2, s3};
#pragma unroll
    for (int j = 0; j < 4; j++) {
      const int r = w + j * 8;
      float logit = ss[j] / (sNq[r] * sNk[lane]) * rs;
      float m = logit;
#pragma unroll
      for (int o = 32; o; o >>= 1) m = fmaxf(m, __shfl_xor(m, o));
      float p = __expf(logit - m);
      float den = p;
#pragma unroll
      for (int o = 32; o; o >>= 1) den += __shfl_xor(den, o);
      sAt[r * 64 + lane] = p / den;
    }
  }
  __syncthreads();

  // Weff rows: V read direct from global (L2-resident), float4 coalesced
  const int jg = t & 31, rw = t >> 5;
  const float* Vh = wvm + (size_t)(h * 64) * 128;
  float* dst = isL ? (WeL + (size_t)(b * 256 + h * 32) * 128)
                   : (WeH + (size_t)(b * 768 + h * 96 + rbase) * 128);
  for (int r = rw; r < 32; r += 16) {
    float4 acc = make_float4(0.f, 0.f, 0.f, 0.f);
    for (int e = 0; e < 64; e++) {
      float a = sAt[r * 64 + e];
      float4 v4 = *(const float4*)&Vh[(size_t)e * 128 + jg * 4];
      acc.x = fmaf(a, v4.x, acc.x);
      acc.y = fmaf(a, v4.y, acc.y);
      acc.z = fmaf(a, v4.z, acc.z);
      acc.w = fmaf(a, v4.w, acc.w);
    }
    *(float4*)&dst[(size_t)r * 128 + jg * 4] = acc;
  }
}

// ================= launcher =================
extern "C" void kernel_launch(void* const* d_in, const int* in_sizes, int n_in,
                              void* d_out, int out_size, void* d_ws, size_t ws_size,
                              hipStream_t stream)
{
  if (ws_size < WS_BYTES) return;
  char* ws = (char*)d_ws;

  const float* x       = (const float*)d_in[0];
  const float* w_down  = (const float*)d_in[1];
  const float* w_mid   = (const float*)d_in[2];
  const float* w_up    = (const float*)d_in[3];
  const float* wq_l    = (const float*)d_in[4];
  const float* wk_m    = (const float*)d_in[5];
  const float* wv_m    = (const float*)d_in[6];
  const float* wq_h    = (const float*)d_in[7];
  const float* rescale = (const float*)d_in[8];
  const float* w_proj_l= (const float*)d_in[9];
  const float* b_proj_l= (const float*)d_in[10];
  const float* w_proj_h= (const float*)d_in[11];
  const float* b_proj_h= (const float*)d_in[12];
  const float* qco_w1  = (const float*)d_in[13];
  const float* qsca_w  = (const float*)d_in[14];
  const float* qsca_b  = (const float*)d_in[15];
  const float* qt1_w   = (const float*)d_in[16];
  const float* qt1_b   = (const float*)d_in[17];
  const float* qt2_w   = (const float*)d_in[18];
  const float* qt2_b   = (const float*)d_in[19];
  const float* rsp_w1  = (const float*)d_in[20];
  const float* rsp_pr  = (const float*)d_in[21];
  const float* rsp_w2  = (const float*)d_in[22];
  const float* c31_w1  = (const float*)d_in[23];
  const float* c31_pr  = (const float*)d_in[24];
  const float* c31_w2  = (const float*)d_in[25];
  const float* c31_w3  = (const float*)d_in[26];
  const float* ln1_g   = (const float*)d_in[27];
  const float* ln1_b   = (const float*)d_in[28];
  const float* ff1_w1  = (const float*)d_in[29];
  const float* ff1_b1  = (const float*)d_in[30];
  const float* ff1_w2  = (const float*)d_in[31];
  const float* ff1_b2  = (const float*)d_in[32];
  const float* ln2_g   = (const float*)d_in[33];
  const float* ln2_b   = (const float*)d_in[34];
  const float* ff2_w1  = (const float*)d_in[35];
  const float* ff2_b1  = (const float*)d_in[36];
  const float* ff2_w2  = (const float*)d_in[37];
  const float* ff2_b2  = (const float*)d_in[38];

  bf16*  zbf   = (bf16*)(ws + OFF_ZBF);
  bf16*  wtq   = (bf16*)(ws + OFF_WTQ);
  bf16*  wtr1  = (bf16*)(ws + OFF_WTR1);
  bf16*  wtr2  = (bf16*)(ws + OFF_WTR2);
  bf16*  wtc1  = (bf16*)(ws + OFF_WTC1);
  bf16*  wtf   = (bf16*)(ws + OFF_WTF);
  float* w1t   = (float*)(ws + OFF_W1T);
  float* scawt = (float*)(ws + OFF_SCAWT);
  float* t1wt  = (float*)(ws + OFF_T1WT);
  float* t2wt  = (float*)(ws + OFF_T2WT);
  bf16*  Gb    = (bf16*)(ws + OFF_GB);
  bf16*  wqlb  = (bf16*)(ws + OFF_WQLB);
  bf16*  wkmb  = (bf16*)(ws + OFF_WKMB);
  bf16*  wqhb  = (bf16*)(ws + OFF_WQHB);
  float* gpart = (float*)(ws + OFF_GPART);
  float* T1    = (float*)(ws + OFF_T1);
  float* UL    = (float*)(ws + OFF_UL);
  float* UK    = (float*)(ws + OFF_UK);
  float* T1H   = (float*)(ws + OFF_T1H);
  float* UH    = (float*)(ws + OFF_UH);
  float* WeL   = (float*)(ws + OFF_WEL);
  float* WeH   = (float*)(ws + OFF_WEH);
  bf16*  acatb = (bf16*)(ws + OFF_ACATB);
  float* tsum  = (float*)(ws + OFF_TSUM);
  float* attb  = (float*)(ws + OFF_ATTB);
  bf16*  hcatb = (bf16*)(ws + OFF_HCATB);
  short* hcatT = (short*)(ws + OFF_HCATT);
  short* midb  = (short*)(ws + OFF_MIDB);
  short* houtb = (short*)(ws + OFF_HOUTB);
  bf16*  wffb  = (bf16*)(ws + OFF_WFFB);
  short* xt    = (short*)(ws + OFF_XT);

  // 0) prep: all weight transforms + x transpose, one launch (3552 blocks)
  k_prep_all<<<dim3(3552), 256, 0, stream>>>(
      w_down, w_mid, w_up, rsp_w1, rsp_w2, c31_w1, wq_l, wk_m, wq_h,
      c31_w3, c31_w2, qco_w1, qsca_w, qt1_w, qt2_w,
      ff1_w1, ff1_w2, ff2_w1, ff2_w2, x,
      wtq, wtr1, wtr2, wtc1, wqlb, wkmb, wqhb, wtf,
      w1t, scawt, t1wt, t2wt, wffb, xt);

  // 1) fused QKV conv 64->384 -> Z (NCHW bf16), 192 oc/block, coalesced out
  k_convq<<<dim3(128, 2, 2), 256, 0, stream>>>(xt, (const short*)wtq, zbf);

  // 2) Gram (18 pairs x 16 k-chunks, XCD-grouped swizzle, 576 blocks)
  k_gramm<<<dim3(576), 256, 0, stream>>>((const short*)zbf, gpart);

  // 2b) merged: Gram reduce -> bf16 Gb | QCO tap sums (1280 blocks)
  k_gt<<<dim3(1280), 256, 0, stream>>>(gpart, Gb, zbf, tsum);

  // 3) MFMA solve chain on Gram blocks (5 jobs, symmetric-G B-operand)
  MJobs5 M5;
  M5.A[0] = (const short*)wqlb; M5.lda[0] = 64;  M5.K[0] = 64;  M5.r0[0] = 0;   M5.c0[0] = 64;  M5.C[0] = T1;  M5.ldc[0] = 128; M5.sC[0] = 32768;  M5.nx[0] = 2;
  M5.A[1] = (const short*)wqlb; M5.lda[1] = 64;  M5.K[1] = 64;  M5.r0[1] = 0;   M5.c0[1] = 0;   M5.C[1] = UL;  M5.ldc[1] = 64;  M5.sC[1] = 16384;  M5.nx[1] = 1;
  M5.A[2] = (const short*)wkmb; M5.lda[2] = 128; M5.K[2] = 128; M5.r0[2] = 64;  M5.c0[2] = 64;  M5.C[2] = UK;  M5.ldc[2] = 128; M5.sC[2] = 65536;  M5.nx[2] = 2;
  M5.A[3] = (const short*)wqhb; M5.lda[3] = 192; M5.K[3] = 192; M5.r0[3] = 192; M5.c0[3] = 64;  M5.C[3] = T1H; M5.ldc[3] = 128; M5.sC[3] = 98304;  M5.nx[3] = 2;
  M5.A[4] = (const short*)wqhb; M5.lda[4] = 192; M5.K[4] = 192; M5.r0[4] = 192; M5.c0[4] = 192; M5.C[4] = UH;  M5.ldc[4] = 192; M5.sC[4] = 147456; M5.nx[4] = 3;
  M5.b0[0] = 0; M5.b0[1] = 8; M5.b0[2] = 12; M5.b0[3] = 28; M5.b0[4] = 52; M5.b0[5] = 88;
  k_mgemm5<<<dim3(88, 2), 256, 0, stream>>>(M5, (const short*)Gb);

  // 3b) merged attention (512-thread blocks, 4-row K reuse): norms + logits + softmax + Weff | QCO tail
  k_attnw<<<dim3(33, 2), 512, 0, stream>>>(
      T1, T1H, UL, UK, UH, wq_l, wk_m, wq_h, wv_m, rescale, WeL, WeH,
      tsum, w1t, scawt, qsca_b, t1wt, qt1_b, t2wt, qt2_b, attb);

  Jobs2 J2;
  J2.A[0] = w_proj_l; J2.B[0] = WeL; J2.K[0] = 256; J2.lda[0] = 256; J2.sB[0] = 32768; J2.nx[0] = 8; J2.co[0] = 0;
  J2.A[1] = w_proj_h; J2.B[1] = WeH; J2.K[1] = 768; J2.lda[1] = 768; J2.sB[1] = 98304; J2.nx[1] = 8; J2.co[1] = 8192;
  J2.b0[0] = 0; J2.b0[1] = 32; J2.b0[2] = 128;
  k_sgemm2b<<<dim3(128, 2), 256, 0, stream>>>(J2, acatb);

  // 4) per-pixel linear map -> Hcat (view-quirk LINEAR layout)
  k_pixm<<<dim3(256, 4, 2), 256, 0, stream>>>((const short*)zbf, (const short*)acatb,
                                              b_proj_l, b_proj_h, hcatb);

  // 4b) view-quirk: transpose to px-major for conv
  k_transph<<<dim3(256, 4, 2), 256, 0, stream>>>((const short*)hcatb, hcatT);

  // 5) ReshapeBlock: 256->64 (+prelu) then 64->64
  k_conv64<1><<<dim3(128, 2, 2), 256, 0, stream>>>(
      hcatT, 256, 4194304L, 256, (const short*)wtr1, midb, rsp_pr);
  k_conv64<0><<<dim3(128, 2, 2), 256, 0, stream>>>(
      midb, 64, 1048576L, 64, (const short*)wtr2, houtb, nullptr);

  // 7) Conv3_1 first conv (+prelu)
  k_conv64<1><<<dim3(128, 2, 2), 256, 0, stream>>>(
      houtb, 64, 1048576L, 64, (const short*)wtc1, midb, c31_pr);

  // 7b+8) fused: folded conv + combine + double-FF -> d_out (NCHW f32)
  k_convff<<<dim3(128, 2, 2), 256, 0, stream>>>(
      midb, (const short*)wtf, houtb, attb, x, (const short*)wffb,
      ln1_g, ln1_b, ff1_b1, ff1_b2, ln2_g, ln2_b, ff2_b1, ff2_b2,
      (float*)d_out);
}